// Round 7
// baseline (540.366 us; speedup 1.0000x reference)
//
#include <hip/hip_runtime.h>
#include <stdint.h>
#include <math.h>

#define TOK 2048
#define DMODEL 4096
#define DFF 14336
#define SEQ 512

typedef float f32x4 __attribute__((ext_vector_type(4)));
typedef float f32x2 __attribute__((ext_vector_type(2)));
typedef short s16x8 __attribute__((ext_vector_type(8)));
typedef unsigned short u16x8 __attribute__((ext_vector_type(8)));

__constant__ float NF4_TAB[16] = {
  -1.0f, -0.6961928009986877f, -0.5250730514526367f, -0.39491748809814453f,
  -0.28444138169288635f, -0.18477343022823334f, -0.09105003625154495f, 0.0f,
  0.07958029955625534f, 0.16093020141124725f, 0.24611230194568634f,
  0.33791524171829224f, 0.44070982933044434f, 0.5626170039176941f,
  0.7229568362236023f, 1.0f };

__device__ __forceinline__ uint16_t f2bf(float f) {
  union { float f; uint32_t u; } x; x.f = f;
  uint32_t r = (x.u + 0x7FFFu + ((x.u >> 16) & 1u)) >> 16;
  return (uint16_t)r;
}
__device__ __forceinline__ float bf2f(uint16_t u) {
  union { uint32_t u; float f; } x; x.u = ((uint32_t)u) << 16;
  return x.f;
}
__device__ __forceinline__ f32x4 mfma16(s16x8 a, s16x8 b, f32x4 c) {
  return __builtin_amdgcn_mfma_f32_16x16x32_bf16(a, b, c, 0, 0, 0);
}
__device__ __forceinline__ void gload_lds16(const void* g, void* l) {
  __builtin_amdgcn_global_load_lds(
    (const __attribute__((address_space(1))) unsigned int*)g,
    (__attribute__((address_space(3))) unsigned int*)l, 16, 0, 0);
}
__device__ __forceinline__ f32x2 pf(float w, f32x2 v, f32x2 acc) {
  f32x2 wv = {w, w};
  return wv * v + acc;
}

// ====== fused A: [rms1 rows | dequant K | lastb + r4i(last rows, f32)] =====
__global__ __launch_bounds__(256) void k_fusedA(const int* __restrict__ ids,
    const float* __restrict__ table, const float* __restrict__ w1,
    uint16_t* __restrict__ rbuf, const int* __restrict__ idxK,
    const float* __restrict__ amK, uint16_t* __restrict__ wbuf,
    const int* __restrict__ maskp, int* __restrict__ lastb,
    float* __restrict__ r4i)
{
  int bid = blockIdx.x, tid = threadIdx.x;
  if (bid < 2048) {
    int t = bid;
    int wv = tid >> 6, l = tid & 63;
    const float* src = table + (size_t)ids[t] * DMODEL;
    int d0 = tid * 16;
    float vals[16];
    float ss = 0.f;
    #pragma unroll
    for (int i = 0; i < 4; ++i) {
      float4 v4 = *(const float4*)(src + d0 + i * 4);
      vals[i*4+0] = v4.x; vals[i*4+1] = v4.y; vals[i*4+2] = v4.z; vals[i*4+3] = v4.w;
      ss += v4.x*v4.x + v4.y*v4.y + v4.z*v4.z + v4.w*v4.w;
    }
    #pragma unroll
    for (int off = 1; off < 64; off <<= 1) ss += __shfl_xor(ss, off);
    __shared__ float red[4];
    if (l == 0) red[wv] = ss;
    __syncthreads();
    float rs = rsqrtf((red[0]+red[1]+red[2]+red[3]) * (1.f/DMODEL) + 1e-5f);
    #pragma unroll
    for (int cth = 0; cth < 2; ++cth) {
      int dd = d0 + cth * 8;
      u16x8 pk;
      #pragma unroll
      for (int j = 0; j < 8; ++j) pk[j] = f2bf(vals[cth*8+j] * rs * w1[dd + j]);
      int dsw = (dd & ~63) | (((((dd >> 3) & 7) ^ (t & 7))) << 3);
      *(u16x8*)(rbuf + (size_t)t * DMODEL + dsw) = pk;
    }
  } else if (bid < 2560) {
    // dequant K weights (1024 x 4096) -> wbuf swizzled bf16
    int base = bid - 2048;
    __shared__ float code[16];
    if (tid < 16) code[tid] = NF4_TAB[tid];
    __syncthreads();
    const int nch = 1024 * DMODEL / 8;
    for (int c = base * 256 + tid; c < nch; c += 512 * 256) {
      int e = c << 3;
      int row = e >> 12;
      int kc = e & 4095;
      float a = amK[c >> 3];
      int4 i0 = *(const int4*)(idxK + e);
      int4 i1 = *(const int4*)(idxK + e + 4);
      u16x8 pk;
      pk[0] = f2bf(code[i0.x] * a);
      pk[1] = f2bf(code[i0.y] * a);
      pk[2] = f2bf(code[i0.z] * a);
      pk[3] = f2bf(code[i0.w] * a);
      pk[4] = f2bf(code[i1.x] * a);
      pk[5] = f2bf(code[i1.y] * a);
      pk[6] = f2bf(code[i1.z] * a);
      pk[7] = f2bf(code[i1.w] * a);
      int dk = (kc & ~63) | (((((kc >> 3) & 7) ^ (row & 7))) << 3);
      *(u16x8*)(wbuf + (size_t)row * DMODEL + dk) = pk;
    }
  } else {
    // lastb[b] and r4i[:, b] (f32 straight from the table, rms1-normalized)
    int b = bid - 2560;
    int wv = tid >> 6, l = tid & 63;
    __shared__ int redi[4];
    __shared__ float redf[4];
    int cnt = 0;
    for (int j = tid; j < SEQ; j += 256) cnt += (maskp[b * SEQ + j] > 0);
    #pragma unroll
    for (int off = 1; off < 64; off <<= 1) cnt += __shfl_xor(cnt, off);
    if (l == 0) redi[wv] = cnt;
    __syncthreads();
    int last = redi[0] + redi[1] + redi[2] + redi[3] - 1;
    if (tid == 0) lastb[b] = last;
    int t = b * SEQ + last;
    const float* src = table + (size_t)ids[t] * DMODEL;
    int d0 = tid * 16;
    float vals[16];
    float ss = 0.f;
    #pragma unroll
    for (int i = 0; i < 4; ++i) {
      float4 v4 = *(const float4*)(src + d0 + i * 4);
      vals[i*4+0] = v4.x; vals[i*4+1] = v4.y; vals[i*4+2] = v4.z; vals[i*4+3] = v4.w;
      ss += v4.x*v4.x + v4.y*v4.y + v4.z*v4.z + v4.w*v4.w;
    }
    #pragma unroll
    for (int off = 1; off < 64; off <<= 1) ss += __shfl_xor(ss, off);
    if (l == 0) redf[wv] = ss;
    __syncthreads();
    float rs = rsqrtf((redf[0]+redf[1]+redf[2]+redf[3]) * (1.f/DMODEL) + 1e-5f);
    #pragma unroll
    for (int i = 0; i < 16; ++i)
      r4i[(d0 + i) * 4 + b] = vals[i] * rs * w1[d0 + i];
  }
}

// ============ q-GEMV (4 rows): q4p[b][n] = r4[b] . Wq[n] ===================
__global__ __launch_bounds__(256) void k_gemv_q(const int* __restrict__ idx,
    const float* __restrict__ am, const float* __restrict__ a4i,
    float* __restrict__ q4p)
{
  __shared__ float code[16];
  if (threadIdx.x < 16) code[threadIdx.x] = NF4_TAB[threadIdx.x];
  __syncthreads();
  int wv = threadIdx.x >> 6, l = threadIdx.x & 63;
  int lhi = l >> 4;
  int n = blockIdx.x * 4 + wv;
  const int4* ip = (const int4*)(idx + (size_t)n * 4096);
  const float* ap = am + (size_t)n * 64;
  f32x2 a01 = {0.f, 0.f}, a23 = {0.f, 0.f};
  #pragma unroll
  for (int kk = 0; kk < 16; ++kk) {
    int4 iv = ip[kk * 64 + l];
    float sc = ap[kk * 4 + lhi];
    float w0 = code[iv.x] * sc, w1 = code[iv.y] * sc;
    float w2 = code[iv.z] * sc, w3 = code[iv.w] * sc;
    const float* A0 = a4i + (kk * 256 + l * 4) * 4;
    f32x4 k0 = *(const f32x4*)(A0);
    f32x4 k1 = *(const f32x4*)(A0 + 4);
    f32x4 k2 = *(const f32x4*)(A0 + 8);
    f32x4 k3 = *(const f32x4*)(A0 + 12);
    a01 = pf(w0, __builtin_shufflevector(k0, k0, 0, 1), a01);
    a23 = pf(w0, __builtin_shufflevector(k0, k0, 2, 3), a23);
    a01 = pf(w1, __builtin_shufflevector(k1, k1, 0, 1), a01);
    a23 = pf(w1, __builtin_shufflevector(k1, k1, 2, 3), a23);
    a01 = pf(w2, __builtin_shufflevector(k2, k2, 0, 1), a01);
    a23 = pf(w2, __builtin_shufflevector(k2, k2, 2, 3), a23);
    a01 = pf(w3, __builtin_shufflevector(k3, k3, 0, 1), a01);
    a23 = pf(w3, __builtin_shufflevector(k3, k3, 2, 3), a23);
  }
  float a0 = a01[0], a1 = a01[1], a2 = a23[0], a3 = a23[1];
  #pragma unroll
  for (int off = 1; off < 64; off <<= 1) {
    a0 += __shfl_xor(a0, off); a1 += __shfl_xor(a1, off);
    a2 += __shfl_xor(a2, off); a3 += __shfl_xor(a3, off);
  }
  if (l == 0) {
    q4p[0 * 4096 + n] = a0;
    q4p[1 * 4096 + n] = a1;
    q4p[2 * 4096 + n] = a2;
    q4p[3 * 4096 + n] = a3;
  }
}

// ======= 8-phase 256x256 split-K(8) GEMM: K-proj only (2048 x 1024) ========
__global__ __launch_bounds__(512, 2) void k_gemmk(
    const uint16_t* __restrict__ A, const uint16_t* __restrict__ W,
    float* __restrict__ pout)
{
  constexpr int K = 4096;   // global row stride
  constexpr int NT = 8;     // 512 K-elems per z-chunk
  __shared__ __align__(1024) uint16_t As_[2 * 256 * 64];
  __shared__ __align__(1024) uint16_t Bs_[2 * 256 * 64];
  const int tid = threadIdx.x;
  const int wid = tid >> 6, l = tid & 63;
  const int wr = wid >> 2, wc = wid & 3;
  int f = blockIdx.x + (blockIdx.y << 2) + (blockIdx.z << 5);
  int fs = ((f & 7) << 5) | (f >> 3);
  const int n0 = (fs & 3) * 256;
  const int m0 = ((fs >> 2) & 7) * 256;
  const int zq = fs >> 5;
  const size_t kbase = (size_t)zq * 512;
  const int lrow = l >> 3, lcb = (l & 7) * 16;

  auto stA = [&](int t, int h) {
    int ta = (t < NT) ? t : (t - NT);
    const char* g = (const char*)A +
        ((size_t)(m0 + h * 128 + wid * 16 + lrow) * K + kbase + ta * 64) * 2 + lcb;
    char* s = (char*)As_ + (t & 1) * 32768 + h * 16384 + wid * 2048;
    gload_lds16(g, s);
    gload_lds16(g + (size_t)8 * K * 2, s + 1024);
  };
  auto stB = [&](int t, int h) {
    int ta = (t < NT) ? t : (t - NT);
    const char* g = (const char*)W +
        ((size_t)(n0 + h * 128 + wid * 16 + lrow) * K + kbase + ta * 64) * 2 + lcb;
    char* s = (char*)Bs_ + (t & 1) * 32768 + h * 16384 + wid * 2048;
    gload_lds16(g, s);
    gload_lds16(g + (size_t)8 * K * 2, s + 1024);
  };

  const int cb0 = (((l >> 4) << 4)) ^ ((l & 7) << 4);
  const int cb1 = (64 + ((l >> 4) << 4)) ^ ((l & 7) << 4);

  const f32x4 Z4 = {0.f, 0.f, 0.f, 0.f};
  f32x4 acc[8][4];
  #pragma unroll
  for (int i = 0; i < 8; ++i)
    #pragma unroll
    for (int j = 0; j < 4; ++j) acc[i][j] = Z4;
  s16x8 bfr[4][2];

#define VMW asm volatile("s_waitcnt vmcnt(6)" ::: "memory")
#define PHASE(DB, Q, READB, STG) {                                          \
    const char* abase = (const char*)As_ + (DB) * 32768;                    \
    s16x8 af[2][2];                                                         \
    _Pragma("unroll") for (int mm = 0; mm < 2; ++mm) {                      \
      int arow = ((2 * (2 * (Q) + mm) + wr) * 16 + (l & 15)) * 128;         \
      af[mm][0] = *(const s16x8*)(abase + arow + cb0);                      \
      af[mm][1] = *(const s16x8*)(abase + arow + cb1);                      \
    }                                                                       \
    if (READB) {                                                            \
      const char* bbase = (const char*)Bs_ + (DB) * 32768;                  \
      _Pragma("unroll") for (int nn = 0; nn < 4; ++nn) {                    \
        int brow = (wc * 64 + nn * 16 + (l & 15)) * 128;                    \
        bfr[nn][0] = *(const s16x8*)(bbase + brow + cb0);                   \
        bfr[nn][1] = *(const s16x8*)(bbase + brow + cb1);                   \
      }                                                                     \
    }                                                                       \
    STG;                                                                    \
    __builtin_amdgcn_s_barrier();                                           \
    asm volatile("s_waitcnt lgkmcnt(0)" ::: "memory");                      \
    __builtin_amdgcn_sched_barrier(0);                                      \
    __builtin_amdgcn_s_setprio(1);                                          \
    _Pragma("unroll") for (int mm = 0; mm < 2; ++mm)                        \
      _Pragma("unroll") for (int nn = 0; nn < 4; ++nn) {                    \
        acc[2 * (Q) + mm][nn] = mfma16(af[mm][0], bfr[nn][0], acc[2 * (Q) + mm][nn]); \
        acc[2 * (Q) + mm][nn] = mfma16(af[mm][1], bfr[nn][1], acc[2 * (Q) + mm][nn]); \
      }                                                                     \
    __builtin_amdgcn_s_setprio(0);                                          \
    __builtin_amdgcn_s_barrier();                                           \
  }

  stB(0, 0); stA(0, 0); stB(0, 1); stA(0, 1);
  stB(1, 0); stA(1, 0); stB(1, 1);
  VMW;
  __builtin_amdgcn_s_barrier();

  for (int it = 0; it < NT / 2; ++it) {
    int t0 = 2 * it, t1 = t0 + 1;
    PHASE(0, 0, 1, stA(t1, 1));
    PHASE(0, 1, 0, stB(t0 + 2, 0));
    PHASE(0, 2, 0, stA(t0 + 2, 0));
    PHASE(0, 3, 0, { stB(t0 + 2, 1); VMW; });
    PHASE(1, 0, 1, stA(t0 + 2, 1));
    PHASE(1, 1, 0, stB(t1 + 2, 0));
    PHASE(1, 2, 0, stA(t1 + 2, 0));
    PHASE(1, 3, 0, { stB(t1 + 2, 1); VMW; });
  }
  asm volatile("s_waitcnt vmcnt(0)" ::: "memory");
  __builtin_amdgcn_s_barrier();
#undef PHASE
#undef VMW

  float* po = pout + (size_t)zq * 2048 * 1024;
  #pragma unroll
  for (int mf = 0; mf < 8; ++mf)
    #pragma unroll
    for (int nf = 0; nf < 4; ++nf)
      #pragma unroll
      for (int r = 0; r < 4; ++r) {
        int row = m0 + (2 * mf + wr) * 16 + ((l >> 4) << 2) + r;
        int col = n0 + wc * 64 + nf * 16 + (l & 15);
        po[(size_t)row * 1024 + col] = acc[mf][nf][r];
      }
}

// ==== kscore: per token t: reduce 8 partials -> k_t, rope, dot with qrot ===
__global__ __launch_bounds__(256) void k_kscore(const float* __restrict__ pbuf,
    const float* __restrict__ q4p, const int* __restrict__ lastb,
    float* __restrict__ scores)
{
  int t = blockIdx.x;
  int b = t >> 9, s = t & 511;
  int tid = threadIdx.x;
  __shared__ float qrot[4096];
  __shared__ float ksum[1024];
  __shared__ float cq[64], sq[64], ck[64], sk[64];
  int last = lastb[b];
  if (tid < 64) {
    float inv = expf(-(float)tid * 0.14391156831212787f);
    float s1, c1, s2, c2;
    sincosf((float)last * inv, &s1, &c1);
    sincosf((float)s * inv, &s2, &c2);
    cq[tid] = c1; sq[tid] = s1; ck[tid] = c2; sk[tid] = s2;
  }
  __syncthreads();
  const float scale = 0.08838834764831845f;
  #pragma unroll
  for (int i = 0; i < 16; ++i) {
    int flat = tid + i * 256;
    int d = flat & 127, j = d & 63;
    float qa  = q4p[b * 4096 + flat];
    float qb2 = q4p[b * 4096 + (flat ^ 64)];
    float v = (d < 64) ? qa * cq[j] - qb2 * sq[j] : qa * cq[j] + qb2 * sq[j];
    qrot[flat] = v * scale;
  }
  int c0 = tid * 4;
  f32x4 ks = {0.f, 0.f, 0.f, 0.f};
  #pragma unroll
  for (int z = 0; z < 8; ++z)
    ks += *(const f32x4*)(pbuf + (size_t)z * 2048 * 1024 + (size_t)t * 1024 + c0);
  *(f32x4*)(ksum + c0) = ks;
  __syncthreads();
  f32x4 part = *(const f32x4*)(ksum + (c0 ^ 64));
  f32x4 krv;
  #pragma unroll
  for (int e = 0; e < 4; ++e) {
    int c = c0 + e, j = c & 63;
    krv[e] = ((c & 64) == 0) ? ks[e] * ck[j] - part[e] * sk[j]
                             : ks[e] * ck[j] + part[e] * sk[j];
  }
  int kvh = tid >> 5;
  float p0 = 0.f, p1 = 0.f, p2 = 0.f, p3 = 0.f;
  #pragma unroll
  for (int e = 0; e < 4; ++e) {
    int d = (c0 + e) & 127;
    float kv = krv[e];
    p0 = fmaf(qrot[(kvh * 4 + 0) * 128 + d], kv, p0);
    p1 = fmaf(qrot[(kvh * 4 + 1) * 128 + d], kv, p1);
    p2 = fmaf(qrot[(kvh * 4 + 2) * 128 + d], kv, p2);
    p3 = fmaf(qrot[(kvh * 4 + 3) * 128 + d], kv, p3);
  }
  #pragma unroll
  for (int off = 1; off < 32; off <<= 1) {
    p0 += __shfl_xor(p0, off); p1 += __shfl_xor(p1, off);
    p2 += __shfl_xor(p2, off); p3 += __shfl_xor(p3, off);
  }
  if ((tid & 31) == 0) {
    scores[((b * 32 + kvh * 4 + 0) << 9) + s] = p0;
    scores[((b * 32 + kvh * 4 + 1) << 9) + s] = p1;
    scores[((b * 32 + kvh * 4 + 2) << 9) + s] = p2;
    scores[((b * 32 + kvh * 4 + 3) << 9) + s] = p3;
  }
}

// ==== smrbar: softmax (8 heads) + rbar = sum_j p_j * r~_j  (j-split x2) ====
// rbar layout: [jq 2][kvh 8][4096][16 = g*4+b] f32
__global__ __launch_bounds__(256) void k_smrbar(const float* __restrict__ scores,
    const uint16_t* __restrict__ rbuf, const int* __restrict__ maskp,
    const int* __restrict__ lastb, float* __restrict__ rbar)
{
  int bx = blockIdx.x;
  int hg = bx & 3, ds = (bx >> 2) & 3, b = (bx >> 4) & 3, jq = bx >> 6;
  int tid = threadIdx.x, wv = tid >> 6, l = tid & 63;
  __shared__ float p[8][512];
  __shared__ float red[4];
  int last = lastb[b];
  for (int i = 0; i < 8; ++i) {
    int hh = hg * 8 + i;
    int j0 = tid, j1 = tid + 256;
    bool ok0 = (j0 <= last) && (maskp[b * 512 + j0] > 0);
    bool ok1 = (j1 <= last) && (maskp[b * 512 + j1] > 0);
    float s0 = ok0 ? scores[((b * 32 + hh) << 9) + j0] : -1e9f;
    float s1v = ok1 ? scores[((b * 32 + hh) << 9) + j1] : -1e9f;
    float m = fmaxf(s0, s1v);
    #pragma unroll
    for (int off = 1; off < 64; off <<= 1) m = fmaxf(m, __shfl_xor(m, off));
    if (l == 0) red[wv] = m;
    __syncthreads();
    m = fmaxf(fmaxf(red[0], red[1]), fmaxf(red[2], red[3]));
    __syncthreads();
    float e0 = __expf(s0 - m), e1 = __expf(s1v - m);
    float sum = e0 + e1;
    #pragma unroll
    for (int off = 1; off < 64; off <<= 1) sum += __shfl_xor(sum, off);
    if (l == 0) red[wv] = sum;
    __syncthreads();
    float inv = 1.f / (red[0] + red[1] + red[2] + red[3]);
    __syncthreads();
    p[i][j0] = e0 * inv;
    p[i][j1] = e1 * inv;
  }
  __syncthreads();
  int d = ds * 1024 + tid * 4;
  int gb = d & ~63, chnk = (d >> 3) & 7, rem = d & 7;
  float acc[8][4];
  #pragma unroll
  for (int i = 0; i < 8; ++i)
    #pragma unroll
    for (int e = 0; e < 4; ++e) acc[i][e] = 0.f;
  int jbase = jq * 256;
  int jend = (last < jbase + 255) ? last : (jbase + 255);
  for (int j = jbase; j <= jend; ++j) {
    int t = b * 512 + j;
    const uint16_t* row = rbuf + (size_t)t * 4096;
    int so = gb + ((chnk ^ (t & 7)) << 3) + rem;
    ushort4 rv = *(const ushort4*)(row + so);
    float r0 = bf2f(rv.x), r1 = bf2f(rv.y), r2 = bf2f(rv.z), r3 = bf2f(rv.w);
    #pragma unroll
    for (int i = 0; i < 8; ++i) {
      float pj = p[i][j];
      acc[i][0] = fmaf(pj, r0, acc[i][0]);
      acc[i][1] = fmaf(pj, r1, acc[i][1]);
      acc[i][2] = fmaf(pj, r2, acc[i][2]);
      acc[i][3] = fmaf(pj, r3, acc[i][3]);
    }
  }
  #pragma unroll
  for (int i = 0; i < 8; ++i) {
    int hh = hg * 8 + i;
    int kvh = hh >> 2, g = hh & 3;
    #pragma unroll
    for (int e = 0; e < 4; ++e)
      rbar[(((size_t)jq * 8 + kvh) * 4096 + d + e) * 16 + g * 4 + b] = acc[i][e];
  }
}

// ==== v-GEMV: ao[b][hh*128+dout] = Wv[n] . rbar[b][hh]  (16 accs/wave) =====
__global__ __launch_bounds__(256) void k_gemv_v(const int* __restrict__ idx,
    const float* __restrict__ am, const float* __restrict__ rbar,
    float* __restrict__ ao4i)
{
  __shared__ float code[16];
  if (threadIdx.x < 16) code[threadIdx.x] = NF4_TAB[threadIdx.x];
  __syncthreads();
  int wv = threadIdx.x >> 6, l = threadIdx.x & 63;
  int lhi = l >> 4;
  int n = blockIdx.x * 4 + wv;   // [0,1024)
  int kvh = n >> 7, dout = n & 127;
  const int4* ip = (const int4*)(idx + (size_t)n * 4096);
  const float* ap = am + (size_t)n * 64;
  const float* rb0 = rbar + (size_t)kvh * 4096 * 16;
  const float* rb1 = rb0 + (size_t)8 * 4096 * 16;
  f32x4 acc[4];
  #pragma unroll
  for (int g = 0; g < 4; ++g) acc[g] = (f32x4){0.f, 0.f, 0.f, 0.f};
  #pragma unroll 4
  for (int kk = 0; kk < 16; ++kk) {
    int4 iv = ip[kk * 64 + l];
    float sc = ap[kk * 4 + lhi];
    float w[4];
    w[0] = code[iv.x] * sc; w[1] = code[iv.y] * sc;
    w[2] = code[iv.z] * sc; w[3] = code[iv.w] * sc;
    int k0 = kk * 256 + l * 4;
    #pragma unroll
    for (int e = 0; e < 4; ++e) {
      const float* base0 = rb0 + (size_t)(k0 + e) * 16;
      const float* base1 = rb1 + (size_t)(k0 + e) * 16;
      f32x4 we = {w[e], w[e], w[e], w[e]};
      #pragma unroll
      for (int g = 0; g < 4; ++g) {
        f32x4 v = *(const f32x4*)(base0 + g * 4) + *(const f32x4*)(base1 + g * 4);
        acc[g] += we * v;
      }
    }
  }
  #pragma unroll
  for (int g = 0; g < 4; ++g)
    #pragma unroll
    for (int c = 0; c < 4; ++c)
      #pragma unroll
      for (int off = 1; off < 64; off <<= 1)
        acc[g][c] += __shfl_xor(acc[g][c], off);
  if (l == 0) {
    #pragma unroll
    for (int g = 0; g < 4; ++g)
      *(f32x4*)(ao4i + (size_t)((kvh * 4 + g) * 128 + dout) * 4) = acc[g];
  }
}

// -------- o-proj 4-row GEMV + embed residual -> h4i [4096][4] --------------
__global__ __launch_bounds__(256) void k_gemv_o(const int* __restrict__ idx,
    const float* __restrict__ am, const float* __restrict__ a4i,
    float* __restrict__ out4i, const float* __restrict__ table,
    const int* __restrict__ ids, const int* __restrict__ lastb)
{
  __shared__ float code[16];
  if (threadIdx.x < 16) code[threadIdx.x] = NF4_TAB[threadIdx.x];
  __syncthreads();
  int wv = threadIdx.x >> 6, l = threadIdx.x & 63;
  int lhi = l >> 4;
  int n = blockIdx.x * 4 + wv;
  const int4* ip = (const int4*)(idx + (size_t)n * 4096);
  const float* ap = am + (size_t)n * 64;
  f32x2 a01 = {0.f, 0.f}, a23 = {0.f, 0.f};
  #pragma unroll
  for (int kk = 0; kk < 16; ++kk) {
    int4 iv = ip[kk * 64 + l];
    float sc = ap[kk * 4 + lhi];
    float w0 = code[iv.x] * sc, w1 = code[iv.y] * sc;
    float w2 = code[iv.z] * sc, w3 = code[iv.w] * sc;
    const float* A0 = a4i + (kk * 256 + l * 4) * 4;
    f32x4 k0 = *(const f32x4*)(A0);
    f32x4 k1 = *(const f32x4*)(A0 + 4);
    f32x4 k2 = *(const f32x4*)(A0 + 8);
    f32x4 k3 = *(const f32x4*)(A0 + 12);
    a01 = pf(w0, __builtin_shufflevector(k0, k0, 0, 1), a01);
    a23 = pf(w0, __builtin_shufflevector(k0, k0, 2, 3), a23);
    a01 = pf(w1, __builtin_shufflevector(k1, k1, 0, 1), a01);
    a23 = pf(w1, __builtin_shufflevector(k1, k1, 2, 3), a23);
    a01 = pf(w2, __builtin_shufflevector(k2, k2, 0, 1), a01);
    a23 = pf(w2, __builtin_shufflevector(k2, k2, 2, 3), a23);
    a01 = pf(w3, __builtin_shufflevector(k3, k3, 0, 1), a01);
    a23 = pf(w3, __builtin_shufflevector(k3, k3, 2, 3), a23);
  }
  float a0 = a01[0], a1 = a01[1], a2 = a23[0], a3 = a23[1];
  #pragma unroll
  for (int off = 1; off < 64; off <<= 1) {
    a0 += __shfl_xor(a0, off); a1 += __shfl_xor(a1, off);
    a2 += __shfl_xor(a2, off); a3 += __shfl_xor(a3, off);
  }
  if (l == 0) {
    f32x4 o;
    o[0] = a0; o[1] = a1; o[2] = a2; o[3] = a3;
    #pragma unroll
    for (int r = 0; r < 4; ++r)
      o[r] += table[(size_t)ids[r * SEQ + lastb[r]] * DMODEL + n];
    *(f32x4*)(out4i + (size_t)n * 4) = o;
  }
}

// ==== gate+up GEMV with inline rms2 (norms recomputed per block, L2-hit) ===
__global__ __launch_bounds__(256) void k_gemv_gu(const int* __restrict__ idxg,
    const float* __restrict__ amg, const int* __restrict__ idxu,
    const float* __restrict__ amu, const float* __restrict__ h4i,
    const float* __restrict__ w2, float* __restrict__ hm4i)
{
  __shared__ float code[16];
  __shared__ f32x4 redv[4];
  int tid = threadIdx.x, wv = tid >> 6, l = tid & 63;
  if (tid < 16) code[tid] = NF4_TAB[tid];
  // rms2 prologue
  f32x4 ssv = {0.f, 0.f, 0.f, 0.f};
  for (int i = 0; i < 16; ++i) {
    f32x4 h = *(const f32x4*)(h4i + (size_t)(tid + i * 256) * 4);
    ssv += h * h;
  }
  #pragma unroll
  for (int off = 1; off < 64; off <<= 1) {
    ssv[0] += __shfl_xor(ssv[0], off);
    ssv[1] += __shfl_xor(ssv[1], off);
    ssv[2] += __shfl_xor(ssv[2], off);
    ssv[3] += __shfl_xor(ssv[3], off);
  }
  if (l == 0) redv[wv] = ssv;
  __syncthreads();
  f32x4 tot = redv[0] + redv[1] + redv[2] + redv[3];
  f32x4 rs;
  #pragma unroll
  for (int r = 0; r < 4; ++r) rs[r] = rsqrtf(tot[r] * (1.f / 4096.f) + 1e-5f);

  int lhi = l >> 4;
  int n = blockIdx.x * 4 + wv;
  const int4* ipg = (const int4*)(idxg + (size_t)n * 4096);
  const int4* ipu = (const int4*)(idxu + (size_t)n * 4096);
  const float* apg = amg + (size_t)n * 64;
  const float* apu = amu + (size_t)n * 64;
  f32x2 g01 = {0.f, 0.f}, g23 = {0.f, 0.f};
  f32x2 u01 = {0.f, 0.f}, u23 = {0.f, 0.f};
  #pragma unroll 8
  for (int kk = 0; kk < 16; ++kk) {
    int4 ig = ipg[kk * 64 + l];
    int4 iu = ipu[kk * 64 + l];
    float sg = apg[kk * 4 + lhi];
    float su = apu[kk * 4 + lhi];
    float wg0 = code[ig.x] * sg, wg1 = code[ig.y] * sg;
    float wg2 = code[ig.z] * sg, wg3 = code[ig.w] * sg;
    float wu0 = code[iu.x] * su, wu1 = code[iu.y] * su;
    float wu2 = code[iu.z] * su, wu3 = code[iu.w] * su;
    int kb = kk * 256 + l * 4;
    const float* H = h4i + (size_t)kb * 4;
    float4 w2v = *(const float4*)(w2 + kb);
    f32x4 k0 = (*(const f32x4*)(H))      * rs * w2v.x;
    f32x4 k1 = (*(const f32x4*)(H + 4))  * rs * w2v.y;
    f32x4 k2 = (*(const f32x4*)(H + 8))  * rs * w2v.z;
    f32x4 k3 = (*(const f32x4*)(H + 12)) * rs * w2v.w;
    f32x2 k0l = __builtin_shufflevector(k0, k0, 0, 1), k0h = __builtin_shufflevector(k0, k0, 2, 3);
    f32x2 k1l = __builtin_shufflevector(k1, k1, 0, 1), k1h = __builtin_shufflevector(k1, k1, 2, 3);
    f32x2 k2l = __builtin_shufflevector(k2, k2, 0, 1), k2h = __builtin_shufflevector(k2, k2, 2, 3);
    f32x2 k3l = __builtin_shufflevector(k3, k3, 0, 1), k3h = __builtin_shufflevector(k3, k3, 2, 3);
    g01 = pf(wg0, k0l, g01); g23 = pf(wg0, k0h, g23);
    g01 = pf(wg1, k1l, g01); g23 = pf(wg1, k1h, g23);
    g01 = pf(wg2, k2l, g01); g23 = pf(wg2, k2h, g23);
    g01 = pf(wg3, k3l, g01); g23 = pf(wg3, k3h, g23);
    u01 = pf(wu0, k0l, u01); u23 = pf(wu0, k0h, u23);
    u01 = pf(wu1, k1l, u01); u23 = pf(wu1, k1h, u23);
    u01 = pf(wu2, k2l, u01); u23 = pf(wu2, k2h, u23);
    u01 = pf(wu3, k3l, u01); u23 = pf(wu3, k3h, u23);
  }
  float g0 = g01[0], g1 = g01[1], g2 = g23[0], g3 = g23[1];
  float u0 = u01[0], u1 = u01[1], u2 = u23[0], u3 = u23[1];
  #pragma unroll
  for (int off = 1; off < 64; off <<= 1) {
    g0 += __shfl_xor(g0, off); g1 += __shfl_xor(g1, off);
    g2 += __shfl_xor(g2, off); g3 += __shfl_xor(g3, off);
    u0 += __shfl_xor(u0, off); u1 += __shfl_xor(u1, off);
    u2 += __shfl_xor(u2, off); u3 += __shfl_xor(u3, off);
  }
  if (l == 0) {
    f32x4 o;
    o[0] = (g0 / (1.f + __expf(-g0))) * u0;
    o[1] = (g1 / (1.f + __expf(-g1))) * u1;
    o[2] = (g2 / (1.f + __expf(-g2))) * u2;
    o[3] = (g3 / (1.f + __expf(-g3))) * u3;
    *(f32x4*)(hm4i + (size_t)n * 4) = o;
  }
}

// -------- down 4-row GEMV (K=14336): h4r[r][n] = h4i[n][r] + dot -----------
__global__ __launch_bounds__(256) void k_gemv_down(const int* __restrict__ idx,
    const float* __restrict__ am, const float* __restrict__ hm4i,
    const float* __restrict__ h4i, float* __restrict__ h4r)
{
  __shared__ float code[16];
  if (threadIdx.x < 16) code[threadIdx.x] = NF4_TAB[threadIdx.x];
  __syncthreads();
  int wv = threadIdx.x >> 6, l = threadIdx.x & 63;
  int lhi = l >> 4;
  int n = blockIdx.x * 4 + wv;
  const int4* ip = (const int4*)(idx + (size_t)n * 14336);
  const float* ap = am + (size_t)n * 224;
  f32x2 a01 = {0.f, 0.f}, a23 = {0.f, 0.f};
  #pragma unroll 8
  for (int kk = 0; kk < 56; ++kk) {
    int4 iv = ip[kk * 64 + l];
    float sc = ap[kk * 4 + lhi];
    float w0 = code[iv.x] * sc, w1 = code[iv.y] * sc;
    float w2 = code[iv.z] * sc, w3 = code[iv.w] * sc;
    const float* A0 = hm4i + (kk * 256 + l * 4) * 4;
    f32x4 k0 = *(const f32x4*)(A0);
    f32x4 k1 = *(const f32x4*)(A0 + 4);
    f32x4 k2 = *(const f32x4*)(A0 + 8);
    f32x4 k3 = *(const f32x4*)(A0 + 12);
    a01 = pf(w0, __builtin_shufflevector(k0, k0, 0, 1), a01);
    a23 = pf(w0, __builtin_shufflevector(k0, k0, 2, 3), a23);
    a01 = pf(w1, __builtin_shufflevector(k1, k1, 0, 1), a01);
    a23 = pf(w1, __builtin_shufflevector(k1, k1, 2, 3), a23);
    a01 = pf(w2, __builtin_shufflevector(k2, k2, 0, 1), a01);
    a23 = pf(w2, __builtin_shufflevector(k2, k2, 2, 3), a23);
    a01 = pf(w3, __builtin_shufflevector(k3, k3, 0, 1), a01);
    a23 = pf(w3, __builtin_shufflevector(k3, k3, 2, 3), a23);
  }
  float a0 = a01[0], a1 = a01[1], a2 = a23[0], a3 = a23[1];
  #pragma unroll
  for (int off = 1; off < 64; off <<= 1) {
    a0 += __shfl_xor(a0, off); a1 += __shfl_xor(a1, off);
    a2 += __shfl_xor(a2, off); a3 += __shfl_xor(a3, off);
  }
  if (l == 0) {
    f32x4 hr = *(const f32x4*)(h4i + (size_t)n * 4);
    h4r[0 * 4096 + n] = hr[0] + a0;
    h4r[1 * 4096 + n] = hr[1] + a1;
    h4r[2 * 4096 + n] = hr[2] + a2;
    h4r[3 * 4096 + n] = hr[3] + a3;
  }
}

// -------- pool (parallel): one block per output column o -------------------
__global__ __launch_bounds__(256) void k_pool3(const float* __restrict__ h4r,
    const float* __restrict__ dpw, const float* __restrict__ dpb,
    float* __restrict__ out)
{
  int o = blockIdx.x;
  int tid = threadIdx.x, wv = tid >> 6, l = tid & 63;
  __shared__ float dsh[4], nsh[4];
  const float* row = h4r + wv * 4096;
  const float* wrow = dpw + (size_t)o * 4096;
  float d1 = 0.f, ss = 0.f;
  for (int d = l * 4; d < 4096; d += 256) {
    float4 v = *(const float4*)(row + d);
    float4 u = *(const float4*)(wrow + d);
    d1 += v.x*u.x + v.y*u.y + v.z*u.z + v.w*u.w;
    ss += v.x*v.x + v.y*v.y + v.z*v.z + v.w*v.w;
  }
  #pragma unroll
  for (int off = 1; off < 64; off <<= 1) {
    d1 += __shfl_xor(d1, off);
    ss += __shfl_xor(ss, off);
  }
  if (l == 0) { dsh[wv] = d1; nsh[wv] = fmaxf(sqrtf(ss), 1e-12f); }
  __syncthreads();
  if (tid < 2) {
    float b = dpb[o];
    float e1 = dsh[tid] / nsh[tid] + b;
    float e2 = dsh[tid + 2] / nsh[tid + 2] + b;
    out[tid * 50 + o] = e1 * e2;
  }
}

// ---------------------------------------------------------------------------
extern "C" void kernel_launch(void* const* d_in, const int* in_sizes, int n_in,
                              void* d_out, int out_size, void* d_ws, size_t ws_size,
                              hipStream_t stream) {
  const int*   ids   = (const int*)d_in[0];
  const int*   maskp = (const int*)d_in[1];
  const float* table = (const float*)d_in[2];
  const int* idxp[7];
  const float* amp[7];
  if (in_sizes[4] == in_sizes[3] / 64) {
    for (int i = 0; i < 7; ++i) {
      idxp[i] = (const int*)d_in[3 + 2 * i];
      amp[i]  = (const float*)d_in[4 + 2 * i];
    }
  } else {
    for (int i = 0; i < 7; ++i) {
      idxp[i] = (const int*)d_in[3 + i];
      amp[i]  = (const float*)d_in[10 + i];
    }
  }
  const float* rms1 = (const float*)d_in[17];
  const float* rms2w = (const float*)d_in[18];
  const float* dpw  = (const float*)d_in[19];
  const float* dpb  = (const float*)d_in[20];
  float* out = (float*)d_out;

  char* p = (char*)d_ws;
  int*      lastb  = (int*)p;      p += 256;
  float*    r4i    = (float*)p;    p += 4 * 4096 * 4;
  float*    q4p    = (float*)p;    p += 4 * 4096 * 4;
  float*    ao4i   = (float*)p;    p += 4 * 4096 * 4;
  float*    h4i    = (float*)p;    p += 4 * 4096 * 4;
  float*    h4r    = (float*)p;    p += 4 * 4096 * 4;
  float*    scores = (float*)p;    p += 4 * 32 * 512 * 4;            // 256 KiB
  float*    hm4i   = (float*)p;    p += (size_t)4 * DFF * 4 + 512;   // 224 KiB
  float*    rbar   = (float*)p;    p += (size_t)2 * 8 * 4096 * 16 * 4; // 4 MiB
  uint16_t* rbuf   = (uint16_t*)p; p += (size_t)TOK * DMODEL * 2;    // 16 MiB
  uint16_t* wbuf   = (uint16_t*)p; p += (size_t)1024 * DMODEL * 2;   // 8 MiB
  float*    pbuf   = (float*)p;    p += (size_t)8 * 2048 * 1024 * 4; // 64 MiB

  // A: rms1 all rows | dequant K | lastb + r4i   (2564 blocks)
  k_fusedA<<<2564, 256, 0, stream>>>(ids, table, rms1, rbuf,
      idxp[1], amp[1], wbuf, maskp, lastb, r4i);

  // q projection at the 4 last tokens
  k_gemv_q<<<1024, 256, 0, stream>>>(idxp[0], amp[0], r4i, q4p);

  // K projection (all tokens), split-K=8, XCD-swizzled
  k_gemmk<<<dim3(4, 8, 8), 512, 0, stream>>>(rbuf, wbuf, pbuf);

  // per-token: reduce partials + rope(k) + rope(q) + q.k  -> scores
  k_kscore<<<2048, 256, 0, stream>>>(pbuf, q4p, lastb, scores);

  // softmax + rbar = sum_j p_j r~_j   (V-projection eliminated by linearity)
  k_smrbar<<<128, 256, 0, stream>>>(scores, rbuf, maskp, lastb, rbar);

  // ao = Wv . rbar
  k_gemv_v<<<256, 256, 0, stream>>>(idxp[2], amp[2], rbar, ao4i);

  // O projection + embed residual -> h4i
  k_gemv_o<<<1024, 256, 0, stream>>>(idxp[3], amp[3], ao4i, h4i, table, ids, lastb);

  // MLP (rms2 inlined in gu)
  k_gemv_gu<<<3584, 256, 0, stream>>>(idxp[4], amp[4], idxp[5], amp[5], h4i, rms2w, hm4i);
  k_gemv_down<<<1024, 256, 0, stream>>>(idxp[6], amp[6], hm4i, h4i, h4r);

  // pool + normalize + project + pairwise product
  k_pool3<<<50, 256, 0, stream>>>(h4r, dpw, dpb, out);
}

// Round 8
// 447.604 us; speedup vs baseline: 1.2072x; 1.2072x over previous
//
#include <hip/hip_runtime.h>
#include <stdint.h>
#include <math.h>

#define TOK 2048
#define DMODEL 4096
#define DFF 14336
#define SEQ 512

typedef float f32x4 __attribute__((ext_vector_type(4)));
typedef float f32x2 __attribute__((ext_vector_type(2)));
typedef short s16x8 __attribute__((ext_vector_type(8)));
typedef unsigned short u16x8 __attribute__((ext_vector_type(8)));

__constant__ float NF4_TAB[16] = {
  -1.0f, -0.6961928009986877f, -0.5250730514526367f, -0.39491748809814453f,
  -0.28444138169288635f, -0.18477343022823334f, -0.09105003625154495f, 0.0f,
  0.07958029955625534f, 0.16093020141124725f, 0.24611230194568634f,
  0.33791524171829224f, 0.44070982933044434f, 0.5626170039176941f,
  0.7229568362236023f, 1.0f };

__device__ __forceinline__ uint16_t f2bf(float f) {
  union { float f; uint32_t u; } x; x.f = f;
  uint32_t r = (x.u + 0x7FFFu + ((x.u >> 16) & 1u)) >> 16;
  return (uint16_t)r;
}
__device__ __forceinline__ float bf2f(uint16_t u) {
  union { uint32_t u; float f; } x; x.u = ((uint32_t)u) << 16;
  return x.f;
}
__device__ __forceinline__ f32x4 mfma16(s16x8 a, s16x8 b, f32x4 c) {
  return __builtin_amdgcn_mfma_f32_16x16x32_bf16(a, b, c, 0, 0, 0);
}
__device__ __forceinline__ void gload_lds16(const void* g, void* l) {
  __builtin_amdgcn_global_load_lds(
    (const __attribute__((address_space(1))) unsigned int*)g,
    (__attribute__((address_space(3))) unsigned int*)l, 16, 0, 0);
}
__device__ __forceinline__ f32x2 pf(float w, f32x2 v, f32x2 acc) {
  f32x2 wv = {w, w};
  return wv * v + acc;
}

// ====== fused A: [rms1 rows | dequant K | lastb + r4i(last rows, f32)] =====
__global__ __launch_bounds__(256) void k_fusedA(const int* __restrict__ ids,
    const float* __restrict__ table, const float* __restrict__ w1,
    uint16_t* __restrict__ rbuf, const int* __restrict__ idxK,
    const float* __restrict__ amK, uint16_t* __restrict__ wbuf,
    const int* __restrict__ maskp, int* __restrict__ lastb,
    float* __restrict__ r4i)
{
  int bid = blockIdx.x, tid = threadIdx.x;
  if (bid < 2048) {
    int t = bid;
    int wv = tid >> 6, l = tid & 63;
    const float* src = table + (size_t)ids[t] * DMODEL;
    int d0 = tid * 16;
    float vals[16];
    float ss = 0.f;
    #pragma unroll
    for (int i = 0; i < 4; ++i) {
      float4 v4 = *(const float4*)(src + d0 + i * 4);
      vals[i*4+0] = v4.x; vals[i*4+1] = v4.y; vals[i*4+2] = v4.z; vals[i*4+3] = v4.w;
      ss += v4.x*v4.x + v4.y*v4.y + v4.z*v4.z + v4.w*v4.w;
    }
    #pragma unroll
    for (int off = 1; off < 64; off <<= 1) ss += __shfl_xor(ss, off);
    __shared__ float red[4];
    if (l == 0) red[wv] = ss;
    __syncthreads();
    float rs = rsqrtf((red[0]+red[1]+red[2]+red[3]) * (1.f/DMODEL) + 1e-5f);
    #pragma unroll
    for (int cth = 0; cth < 2; ++cth) {
      int dd = d0 + cth * 8;
      u16x8 pk;
      #pragma unroll
      for (int j = 0; j < 8; ++j) pk[j] = f2bf(vals[cth*8+j] * rs * w1[dd + j]);
      int dsw = (dd & ~63) | (((((dd >> 3) & 7) ^ (t & 7))) << 3);
      *(u16x8*)(rbuf + (size_t)t * DMODEL + dsw) = pk;
    }
  } else if (bid < 2560) {
    int base = bid - 2048;
    __shared__ float code[16];
    if (tid < 16) code[tid] = NF4_TAB[tid];
    __syncthreads();
    const int nch = 1024 * DMODEL / 8;
    for (int c = base * 256 + tid; c < nch; c += 512 * 256) {
      int e = c << 3;
      int row = e >> 12;
      int kc = e & 4095;
      float a = amK[c >> 3];
      int4 i0 = *(const int4*)(idxK + e);
      int4 i1 = *(const int4*)(idxK + e + 4);
      u16x8 pk;
      pk[0] = f2bf(code[i0.x] * a);
      pk[1] = f2bf(code[i0.y] * a);
      pk[2] = f2bf(code[i0.z] * a);
      pk[3] = f2bf(code[i0.w] * a);
      pk[4] = f2bf(code[i1.x] * a);
      pk[5] = f2bf(code[i1.y] * a);
      pk[6] = f2bf(code[i1.z] * a);
      pk[7] = f2bf(code[i1.w] * a);
      int dk = (kc & ~63) | (((((kc >> 3) & 7) ^ (row & 7))) << 3);
      *(u16x8*)(wbuf + (size_t)row * DMODEL + dk) = pk;
    }
  } else {
    int b = bid - 2560;
    int wv = tid >> 6, l = tid & 63;
    __shared__ int redi[4];
    __shared__ float redf[4];
    int cnt = 0;
    for (int j = tid; j < SEQ; j += 256) cnt += (maskp[b * SEQ + j] > 0);
    #pragma unroll
    for (int off = 1; off < 64; off <<= 1) cnt += __shfl_xor(cnt, off);
    if (l == 0) redi[wv] = cnt;
    __syncthreads();
    int last = redi[0] + redi[1] + redi[2] + redi[3] - 1;
    if (tid == 0) lastb[b] = last;
    int t = b * SEQ + last;
    const float* src = table + (size_t)ids[t] * DMODEL;
    int d0 = tid * 16;
    float vals[16];
    float ss = 0.f;
    #pragma unroll
    for (int i = 0; i < 4; ++i) {
      float4 v4 = *(const float4*)(src + d0 + i * 4);
      vals[i*4+0] = v4.x; vals[i*4+1] = v4.y; vals[i*4+2] = v4.z; vals[i*4+3] = v4.w;
      ss += v4.x*v4.x + v4.y*v4.y + v4.z*v4.z + v4.w*v4.w;
    }
    #pragma unroll
    for (int off = 1; off < 64; off <<= 1) ss += __shfl_xor(ss, off);
    if (l == 0) redf[wv] = ss;
    __syncthreads();
    float rs = rsqrtf((redf[0]+redf[1]+redf[2]+redf[3]) * (1.f/DMODEL) + 1e-5f);
    #pragma unroll
    for (int i = 0; i < 16; ++i)
      r4i[(d0 + i) * 4 + b] = vals[i] * rs * w1[d0 + i];
  }
}

// ============ q-GEMV (4 rows): q4p[b][n] = r4[b] . Wq[n] ===================
__global__ __launch_bounds__(256) void k_gemv_q(const int* __restrict__ idx,
    const float* __restrict__ am, const float* __restrict__ a4i,
    float* __restrict__ q4p)
{
  __shared__ float code[16];
  if (threadIdx.x < 16) code[threadIdx.x] = NF4_TAB[threadIdx.x];
  __syncthreads();
  int wv = threadIdx.x >> 6, l = threadIdx.x & 63;
  int lhi = l >> 4;
  int n = blockIdx.x * 4 + wv;
  const int4* ip = (const int4*)(idx + (size_t)n * 4096);
  const float* ap = am + (size_t)n * 64;
  f32x2 a01 = {0.f, 0.f}, a23 = {0.f, 0.f};
  #pragma unroll
  for (int kk = 0; kk < 16; ++kk) {
    int4 iv = ip[kk * 64 + l];
    float sc = ap[kk * 4 + lhi];
    float w0 = code[iv.x] * sc, w1 = code[iv.y] * sc;
    float w2 = code[iv.z] * sc, w3 = code[iv.w] * sc;
    const float* A0 = a4i + (kk * 256 + l * 4) * 4;
    f32x4 k0 = *(const f32x4*)(A0);
    f32x4 k1 = *(const f32x4*)(A0 + 4);
    f32x4 k2 = *(const f32x4*)(A0 + 8);
    f32x4 k3 = *(const f32x4*)(A0 + 12);
    a01 = pf(w0, __builtin_shufflevector(k0, k0, 0, 1), a01);
    a23 = pf(w0, __builtin_shufflevector(k0, k0, 2, 3), a23);
    a01 = pf(w1, __builtin_shufflevector(k1, k1, 0, 1), a01);
    a23 = pf(w1, __builtin_shufflevector(k1, k1, 2, 3), a23);
    a01 = pf(w2, __builtin_shufflevector(k2, k2, 0, 1), a01);
    a23 = pf(w2, __builtin_shufflevector(k2, k2, 2, 3), a23);
    a01 = pf(w3, __builtin_shufflevector(k3, k3, 0, 1), a01);
    a23 = pf(w3, __builtin_shufflevector(k3, k3, 2, 3), a23);
  }
  float a0 = a01[0], a1 = a01[1], a2 = a23[0], a3 = a23[1];
  #pragma unroll
  for (int off = 1; off < 64; off <<= 1) {
    a0 += __shfl_xor(a0, off); a1 += __shfl_xor(a1, off);
    a2 += __shfl_xor(a2, off); a3 += __shfl_xor(a3, off);
  }
  if (l == 0) {
    q4p[0 * 4096 + n] = a0;
    q4p[1 * 4096 + n] = a1;
    q4p[2 * 4096 + n] = a2;
    q4p[3 * 4096 + n] = a3;
  }
}

// ======= 8-phase 256x256 split-K(8) GEMM: K-proj only (2048 x 1024) ========
__global__ __launch_bounds__(512, 2) void k_gemmk(
    const uint16_t* __restrict__ A, const uint16_t* __restrict__ W,
    float* __restrict__ pout)
{
  constexpr int K = 4096;
  constexpr int NT = 8;
  __shared__ __align__(1024) uint16_t As_[2 * 256 * 64];
  __shared__ __align__(1024) uint16_t Bs_[2 * 256 * 64];
  const int tid = threadIdx.x;
  const int wid = tid >> 6, l = tid & 63;
  const int wr = wid >> 2, wc = wid & 3;
  int f = blockIdx.x + (blockIdx.y << 2) + (blockIdx.z << 5);
  int fs = ((f & 7) << 5) | (f >> 3);
  const int n0 = (fs & 3) * 256;
  const int m0 = ((fs >> 2) & 7) * 256;
  const int zq = fs >> 5;
  const size_t kbase = (size_t)zq * 512;
  const int lrow = l >> 3, lcb = (l & 7) * 16;

  auto stA = [&](int t, int h) {
    int ta = (t < NT) ? t : (t - NT);
    const char* g = (const char*)A +
        ((size_t)(m0 + h * 128 + wid * 16 + lrow) * K + kbase + ta * 64) * 2 + lcb;
    char* s = (char*)As_ + (t & 1) * 32768 + h * 16384 + wid * 2048;
    gload_lds16(g, s);
    gload_lds16(g + (size_t)8 * K * 2, s + 1024);
  };
  auto stB = [&](int t, int h) {
    int ta = (t < NT) ? t : (t - NT);
    const char* g = (const char*)W +
        ((size_t)(n0 + h * 128 + wid * 16 + lrow) * K + kbase + ta * 64) * 2 + lcb;
    char* s = (char*)Bs_ + (t & 1) * 32768 + h * 16384 + wid * 2048;
    gload_lds16(g, s);
    gload_lds16(g + (size_t)8 * K * 2, s + 1024);
  };

  const int cb0 = (((l >> 4) << 4)) ^ ((l & 7) << 4);
  const int cb1 = (64 + ((l >> 4) << 4)) ^ ((l & 7) << 4);

  const f32x4 Z4 = {0.f, 0.f, 0.f, 0.f};
  f32x4 acc[8][4];
  #pragma unroll
  for (int i = 0; i < 8; ++i)
    #pragma unroll
    for (int j = 0; j < 4; ++j) acc[i][j] = Z4;
  s16x8 bfr[4][2];

#define VMW asm volatile("s_waitcnt vmcnt(6)" ::: "memory")
#define PHASE(DB, Q, READB, STG) {                                          \
    const char* abase = (const char*)As_ + (DB) * 32768;                    \
    s16x8 af[2][2];                                                         \
    _Pragma("unroll") for (int mm = 0; mm < 2; ++mm) {                      \
      int arow = ((2 * (2 * (Q) + mm) + wr) * 16 + (l & 15)) * 128;         \
      af[mm][0] = *(const s16x8*)(abase + arow + cb0);                      \
      af[mm][1] = *(const s16x8*)(abase + arow + cb1);                      \
    }                                                                       \
    if (READB) {                                                            \
      const char* bbase = (const char*)Bs_ + (DB) * 32768;                  \
      _Pragma("unroll") for (int nn = 0; nn < 4; ++nn) {                    \
        int brow = (wc * 64 + nn * 16 + (l & 15)) * 128;                    \
        bfr[nn][0] = *(const s16x8*)(bbase + brow + cb0);                   \
        bfr[nn][1] = *(const s16x8*)(bbase + brow + cb1);                   \
      }                                                                     \
    }                                                                       \
    STG;                                                                    \
    __builtin_amdgcn_s_barrier();                                           \
    asm volatile("s_waitcnt lgkmcnt(0)" ::: "memory");                      \
    __builtin_amdgcn_sched_barrier(0);                                      \
    __builtin_amdgcn_s_setprio(1);                                          \
    _Pragma("unroll") for (int mm = 0; mm < 2; ++mm)                        \
      _Pragma("unroll") for (int nn = 0; nn < 4; ++nn) {                    \
        acc[2 * (Q) + mm][nn] = mfma16(af[mm][0], bfr[nn][0], acc[2 * (Q) + mm][nn]); \
        acc[2 * (Q) + mm][nn] = mfma16(af[mm][1], bfr[nn][1], acc[2 * (Q) + mm][nn]); \
      }                                                                     \
    __builtin_amdgcn_s_setprio(0);                                          \
    __builtin_amdgcn_s_barrier();                                           \
  }

  stB(0, 0); stA(0, 0); stB(0, 1); stA(0, 1);
  stB(1, 0); stA(1, 0); stB(1, 1);
  VMW;
  __builtin_amdgcn_s_barrier();

  for (int it = 0; it < NT / 2; ++it) {
    int t0 = 2 * it, t1 = t0 + 1;
    PHASE(0, 0, 1, stA(t1, 1));
    PHASE(0, 1, 0, stB(t0 + 2, 0));
    PHASE(0, 2, 0, stA(t0 + 2, 0));
    PHASE(0, 3, 0, { stB(t0 + 2, 1); VMW; });
    PHASE(1, 0, 1, stA(t0 + 2, 1));
    PHASE(1, 1, 0, stB(t1 + 2, 0));
    PHASE(1, 2, 0, stA(t1 + 2, 0));
    PHASE(1, 3, 0, { stB(t1 + 2, 1); VMW; });
  }
  asm volatile("s_waitcnt vmcnt(0)" ::: "memory");
  __builtin_amdgcn_s_barrier();
#undef PHASE
#undef VMW

  float* po = pout + (size_t)zq * 2048 * 1024;
  #pragma unroll
  for (int mf = 0; mf < 8; ++mf)
    #pragma unroll
    for (int nf = 0; nf < 4; ++nf)
      #pragma unroll
      for (int r = 0; r < 4; ++r) {
        int row = m0 + (2 * mf + wr) * 16 + ((l >> 4) << 2) + r;
        int col = n0 + wc * 64 + nf * 16 + (l & 15);
        po[(size_t)row * 1024 + col] = acc[mf][nf][r];
      }
}

// ==== kscore: per token t: reduce 8 partials -> k_t, rope, dot with qrot ===
__global__ __launch_bounds__(256) void k_kscore(const float* __restrict__ pbuf,
    const float* __restrict__ q4p, const int* __restrict__ lastb,
    float* __restrict__ scores)
{
  int t = blockIdx.x;
  int b = t >> 9, s = t & 511;
  int tid = threadIdx.x;
  __shared__ float qrot[4096];
  __shared__ float ksum[1024];
  __shared__ float cq[64], sq[64], ck[64], sk[64];
  int last = lastb[b];
  if (tid < 64) {
    float inv = expf(-(float)tid * 0.14391156831212787f);
    float s1, c1, s2, c2;
    sincosf((float)last * inv, &s1, &c1);
    sincosf((float)s * inv, &s2, &c2);
    cq[tid] = c1; sq[tid] = s1; ck[tid] = c2; sk[tid] = s2;
  }
  __syncthreads();
  const float scale = 0.08838834764831845f;
  #pragma unroll
  for (int i = 0; i < 16; ++i) {
    int flat = tid + i * 256;
    int d = flat & 127, j = d & 63;
    float qa  = q4p[b * 4096 + flat];
    float qb2 = q4p[b * 4096 + (flat ^ 64)];
    float v = (d < 64) ? qa * cq[j] - qb2 * sq[j] : qa * cq[j] + qb2 * sq[j];
    qrot[flat] = v * scale;
  }
  int c0 = tid * 4;
  f32x4 ks = {0.f, 0.f, 0.f, 0.f};
  #pragma unroll
  for (int z = 0; z < 8; ++z)
    ks += *(const f32x4*)(pbuf + (size_t)z * 2048 * 1024 + (size_t)t * 1024 + c0);
  *(f32x4*)(ksum + c0) = ks;
  __syncthreads();
  f32x4 part = *(const f32x4*)(ksum + (c0 ^ 64));
  f32x4 krv;
  #pragma unroll
  for (int e = 0; e < 4; ++e) {
    int c = c0 + e, j = c & 63;
    krv[e] = ((c & 64) == 0) ? ks[e] * ck[j] - part[e] * sk[j]
                             : ks[e] * ck[j] + part[e] * sk[j];
  }
  int kvh = tid >> 5;
  float p0 = 0.f, p1 = 0.f, p2 = 0.f, p3 = 0.f;
  #pragma unroll
  for (int e = 0; e < 4; ++e) {
    int d = (c0 + e) & 127;
    float kv = krv[e];
    p0 = fmaf(qrot[(kvh * 4 + 0) * 128 + d], kv, p0);
    p1 = fmaf(qrot[(kvh * 4 + 1) * 128 + d], kv, p1);
    p2 = fmaf(qrot[(kvh * 4 + 2) * 128 + d], kv, p2);
    p3 = fmaf(qrot[(kvh * 4 + 3) * 128 + d], kv, p3);
  }
  #pragma unroll
  for (int off = 1; off < 32; off <<= 1) {
    p0 += __shfl_xor(p0, off); p1 += __shfl_xor(p1, off);
    p2 += __shfl_xor(p2, off); p3 += __shfl_xor(p3, off);
  }
  if ((tid & 31) == 0) {
    scores[((b * 32 + kvh * 4 + 0) << 9) + s] = p0;
    scores[((b * 32 + kvh * 4 + 1) << 9) + s] = p1;
    scores[((b * 32 + kvh * 4 + 2) << 9) + s] = p2;
    scores[((b * 32 + kvh * 4 + 3) << 9) + s] = p3;
  }
}

// ==== smrbar v2: softmax (8 heads) + partial rbar over 64-j slice ==========
// grid 512 = hg(4) x ds(4) x b(4) x jq(8). rbar8: [jq8][kvh8][4096][16]
__global__ __launch_bounds__(256) void k_smrbar(const float* __restrict__ scores,
    const uint16_t* __restrict__ rbuf, const int* __restrict__ maskp,
    const int* __restrict__ lastb, float* __restrict__ rbar8)
{
  int bx = blockIdx.x;
  int hg = bx & 3, ds = (bx >> 2) & 3, b = (bx >> 4) & 3, jq = bx >> 6;
  int tid = threadIdx.x, wv = tid >> 6, l = tid & 63;
  __shared__ float p[8][512];
  __shared__ float red[4];
  int last = lastb[b];
  for (int i = 0; i < 8; ++i) {
    int hh = hg * 8 + i;
    int j0 = tid, j1 = tid + 256;
    bool ok0 = (j0 <= last) && (maskp[b * 512 + j0] > 0);
    bool ok1 = (j1 <= last) && (maskp[b * 512 + j1] > 0);
    float s0 = ok0 ? scores[((b * 32 + hh) << 9) + j0] : -1e9f;
    float s1v = ok1 ? scores[((b * 32 + hh) << 9) + j1] : -1e9f;
    float m = fmaxf(s0, s1v);
    #pragma unroll
    for (int off = 1; off < 64; off <<= 1) m = fmaxf(m, __shfl_xor(m, off));
    if (l == 0) red[wv] = m;
    __syncthreads();
    m = fmaxf(fmaxf(red[0], red[1]), fmaxf(red[2], red[3]));
    __syncthreads();
    float e0 = __expf(s0 - m), e1 = __expf(s1v - m);
    float sum = e0 + e1;
    #pragma unroll
    for (int off = 1; off < 64; off <<= 1) sum += __shfl_xor(sum, off);
    if (l == 0) red[wv] = sum;
    __syncthreads();
    float inv = 1.f / (red[0] + red[1] + red[2] + red[3]);
    __syncthreads();
    p[i][j0] = e0 * inv;
    p[i][j1] = e1 * inv;
  }
  __syncthreads();
  int d = ds * 1024 + tid * 4;
  int gb = d & ~63, chnk = (d >> 3) & 7, rem = d & 7;
  float acc[8][4];
  #pragma unroll
  for (int i = 0; i < 8; ++i)
    #pragma unroll
    for (int e = 0; e < 4; ++e) acc[i][e] = 0.f;
  const uint16_t* rb = rbuf + (size_t)(b * 512) * 4096;
  int jbase = jq * 64;
  int jend = (last < jbase + 63) ? last : (jbase + 63);
  int j = jbase;
  // 4-deep unrolled main loop: 4 independent loads in flight
  for (; j + 3 <= jend; j += 4) {
    ushort4 rv[4];
    #pragma unroll
    for (int u = 0; u < 4; ++u) {
      int jj = j + u;
      int so = gb + ((chnk ^ (jj & 7)) << 3) + rem;
      rv[u] = *(const ushort4*)(rb + (size_t)jj * 4096 + so);
    }
    #pragma unroll
    for (int u = 0; u < 4; ++u) {
      float r0 = bf2f(rv[u].x), r1 = bf2f(rv[u].y);
      float r2 = bf2f(rv[u].z), r3 = bf2f(rv[u].w);
      #pragma unroll
      for (int i = 0; i < 8; ++i) {
        float pj = p[i][j + u];
        acc[i][0] = fmaf(pj, r0, acc[i][0]);
        acc[i][1] = fmaf(pj, r1, acc[i][1]);
        acc[i][2] = fmaf(pj, r2, acc[i][2]);
        acc[i][3] = fmaf(pj, r3, acc[i][3]);
      }
    }
  }
  for (; j <= jend; ++j) {
    int so = gb + ((chnk ^ (j & 7)) << 3) + rem;
    ushort4 rv = *(const ushort4*)(rb + (size_t)j * 4096 + so);
    float r0 = bf2f(rv.x), r1 = bf2f(rv.y), r2 = bf2f(rv.z), r3 = bf2f(rv.w);
    #pragma unroll
    for (int i = 0; i < 8; ++i) {
      float pj = p[i][j];
      acc[i][0] = fmaf(pj, r0, acc[i][0]);
      acc[i][1] = fmaf(pj, r1, acc[i][1]);
      acc[i][2] = fmaf(pj, r2, acc[i][2]);
      acc[i][3] = fmaf(pj, r3, acc[i][3]);
    }
  }
  #pragma unroll
  for (int i = 0; i < 8; ++i) {
    int hh = hg * 8 + i;
    int kvh = hh >> 2, g = hh & 3;
    #pragma unroll
    for (int e = 0; e < 4; ++e)
      rbar8[(((size_t)jq * 8 + kvh) * 4096 + d + e) * 16 + g * 4 + b] = acc[i][e];
  }
}

// ==== reduce 8 jq slices -> rbarS [kvh8][4096][16] =========================
__global__ __launch_bounds__(256) void k_rbar_red(const float* __restrict__ rbar8,
    float* __restrict__ rbarS)
{
  size_t i = ((size_t)blockIdx.x * 256 + threadIdx.x) * 4;
  f32x4 s = {0.f, 0.f, 0.f, 0.f};
  #pragma unroll
  for (int jq = 0; jq < 8; ++jq)
    s += *(const f32x4*)(rbar8 + (size_t)jq * 524288 + i);
  *(f32x4*)(rbarS + i) = s;
}

// ==== v-GEMV: ao[b][hh*128+dout] = Wv[n] . rbarS[kvh]  (16 accs/wave) ======
__global__ __launch_bounds__(256) void k_gemv_v(const int* __restrict__ idx,
    const float* __restrict__ am, const float* __restrict__ rbarS,
    float* __restrict__ ao4i)
{
  __shared__ float code[16];
  if (threadIdx.x < 16) code[threadIdx.x] = NF4_TAB[threadIdx.x];
  __syncthreads();
  int wv = threadIdx.x >> 6, l = threadIdx.x & 63;
  int lhi = l >> 4;
  int n = blockIdx.x * 4 + wv;   // [0,1024)
  int kvh = n >> 7, dout = n & 127;
  const int4* ip = (const int4*)(idx + (size_t)n * 4096);
  const float* ap = am + (size_t)n * 64;
  const float* rb0 = rbarS + (size_t)kvh * 4096 * 16;
  f32x4 acc[4];
  #pragma unroll
  for (int g = 0; g < 4; ++g) acc[g] = (f32x4){0.f, 0.f, 0.f, 0.f};
  #pragma unroll 4
  for (int kk = 0; kk < 16; ++kk) {
    int4 iv = ip[kk * 64 + l];
    float sc = ap[kk * 4 + lhi];
    float w[4];
    w[0] = code[iv.x] * sc; w[1] = code[iv.y] * sc;
    w[2] = code[iv.z] * sc; w[3] = code[iv.w] * sc;
    int k0 = kk * 256 + l * 4;
    #pragma unroll
    for (int e = 0; e < 4; ++e) {
      const float* base0 = rb0 + (size_t)(k0 + e) * 16;
      f32x4 we = {w[e], w[e], w[e], w[e]};
      #pragma unroll
      for (int g = 0; g < 4; ++g) {
        f32x4 v = *(const f32x4*)(base0 + g * 4);
        acc[g] += we * v;
      }
    }
  }
  #pragma unroll
  for (int g = 0; g < 4; ++g)
    #pragma unroll
    for (int c = 0; c < 4; ++c)
      #pragma unroll
      for (int off = 1; off < 64; off <<= 1)
        acc[g][c] += __shfl_xor(acc[g][c], off);
  if (l == 0) {
    #pragma unroll
    for (int g = 0; g < 4; ++g)
      *(f32x4*)(ao4i + (size_t)((kvh * 4 + g) * 128 + dout) * 4) = acc[g];
  }
}

// -------- o-proj 4-row GEMV + embed residual -> h4i [4096][4] --------------
__global__ __launch_bounds__(256) void k_gemv_o(const int* __restrict__ idx,
    const float* __restrict__ am, const float* __restrict__ a4i,
    float* __restrict__ out4i, const float* __restrict__ table,
    const int* __restrict__ ids, const int* __restrict__ lastb)
{
  __shared__ float code[16];
  if (threadIdx.x < 16) code[threadIdx.x] = NF4_TAB[threadIdx.x];
  __syncthreads();
  int wv = threadIdx.x >> 6, l = threadIdx.x & 63;
  int lhi = l >> 4;
  int n = blockIdx.x * 4 + wv;
  const int4* ip = (const int4*)(idx + (size_t)n * 4096);
  const float* ap = am + (size_t)n * 64;
  f32x2 a01 = {0.f, 0.f}, a23 = {0.f, 0.f};
  #pragma unroll
  for (int kk = 0; kk < 16; ++kk) {
    int4 iv = ip[kk * 64 + l];
    float sc = ap[kk * 4 + lhi];
    float w0 = code[iv.x] * sc, w1 = code[iv.y] * sc;
    float w2 = code[iv.z] * sc, w3 = code[iv.w] * sc;
    const float* A0 = a4i + (kk * 256 + l * 4) * 4;
    f32x4 k0 = *(const f32x4*)(A0);
    f32x4 k1 = *(const f32x4*)(A0 + 4);
    f32x4 k2 = *(const f32x4*)(A0 + 8);
    f32x4 k3 = *(const f32x4*)(A0 + 12);
    a01 = pf(w0, __builtin_shufflevector(k0, k0, 0, 1), a01);
    a23 = pf(w0, __builtin_shufflevector(k0, k0, 2, 3), a23);
    a01 = pf(w1, __builtin_shufflevector(k1, k1, 0, 1), a01);
    a23 = pf(w1, __builtin_shufflevector(k1, k1, 2, 3), a23);
    a01 = pf(w2, __builtin_shufflevector(k2, k2, 0, 1), a01);
    a23 = pf(w2, __builtin_shufflevector(k2, k2, 2, 3), a23);
    a01 = pf(w3, __builtin_shufflevector(k3, k3, 0, 1), a01);
    a23 = pf(w3, __builtin_shufflevector(k3, k3, 2, 3), a23);
  }
  float a0 = a01[0], a1 = a01[1], a2 = a23[0], a3 = a23[1];
  #pragma unroll
  for (int off = 1; off < 64; off <<= 1) {
    a0 += __shfl_xor(a0, off); a1 += __shfl_xor(a1, off);
    a2 += __shfl_xor(a2, off); a3 += __shfl_xor(a3, off);
  }
  if (l == 0) {
    f32x4 o;
    o[0] = a0; o[1] = a1; o[2] = a2; o[3] = a3;
    #pragma unroll
    for (int r = 0; r < 4; ++r)
      o[r] += table[(size_t)ids[r * SEQ + lastb[r]] * DMODEL + n];
    *(f32x4*)(out4i + (size_t)n * 4) = o;
  }
}

// ==== gate+up GEMV with inline rms2 =========================================
__global__ __launch_bounds__(256) void k_gemv_gu(const int* __restrict__ idxg,
    const float* __restrict__ amg, const int* __restrict__ idxu,
    const float* __restrict__ amu, const float* __restrict__ h4i,
    const float* __restrict__ w2, float* __restrict__ hm4i)
{
  __shared__ float code[16];
  __shared__ f32x4 redv[4];
  int tid = threadIdx.x, wv = tid >> 6, l = tid & 63;
  if (tid < 16) code[tid] = NF4_TAB[tid];
  f32x4 ssv = {0.f, 0.f, 0.f, 0.f};
  for (int i = 0; i < 16; ++i) {
    f32x4 h = *(const f32x4*)(h4i + (size_t)(tid + i * 256) * 4);
    ssv += h * h;
  }
  #pragma unroll
  for (int off = 1; off < 64; off <<= 1) {
    ssv[0] += __shfl_xor(ssv[0], off);
    ssv[1] += __shfl_xor(ssv[1], off);
    ssv[2] += __shfl_xor(ssv[2], off);
    ssv[3] += __shfl_xor(ssv[3], off);
  }
  if (l == 0) redv[wv] = ssv;
  __syncthreads();
  f32x4 tot = redv[0] + redv[1] + redv[2] + redv[3];
  f32x4 rs;
  #pragma unroll
  for (int r = 0; r < 4; ++r) rs[r] = rsqrtf(tot[r] * (1.f / 4096.f) + 1e-5f);

  int lhi = l >> 4;
  int n = blockIdx.x * 4 + wv;
  const int4* ipg = (const int4*)(idxg + (size_t)n * 4096);
  const int4* ipu = (const int4*)(idxu + (size_t)n * 4096);
  const float* apg = amg + (size_t)n * 64;
  const float* apu = amu + (size_t)n * 64;
  f32x2 g01 = {0.f, 0.f}, g23 = {0.f, 0.f};
  f32x2 u01 = {0.f, 0.f}, u23 = {0.f, 0.f};
  #pragma unroll 8
  for (int kk = 0; kk < 16; ++kk) {
    int4 ig = ipg[kk * 64 + l];
    int4 iu = ipu[kk * 64 + l];
    float sg = apg[kk * 4 + lhi];
    float su = apu[kk * 4 + lhi];
    float wg0 = code[ig.x] * sg, wg1 = code[ig.y] * sg;
    float wg2 = code[ig.z] * sg, wg3 = code[ig.w] * sg;
    float wu0 = code[iu.x] * su, wu1 = code[iu.y] * su;
    float wu2 = code[iu.z] * su, wu3 = code[iu.w] * su;
    int kb = kk * 256 + l * 4;
    const float* H = h4i + (size_t)kb * 4;
    float4 w2v = *(const float4*)(w2 + kb);
    f32x4 k0 = (*(const f32x4*)(H))      * rs * w2v.x;
    f32x4 k1 = (*(const f32x4*)(H + 4))  * rs * w2v.y;
    f32x4 k2 = (*(const f32x4*)(H + 8))  * rs * w2v.z;
    f32x4 k3 = (*(const f32x4*)(H + 12)) * rs * w2v.w;
    f32x2 k0l = __builtin_shufflevector(k0, k0, 0, 1), k0h = __builtin_shufflevector(k0, k0, 2, 3);
    f32x2 k1l = __builtin_shufflevector(k1, k1, 0, 1), k1h = __builtin_shufflevector(k1, k1, 2, 3);
    f32x2 k2l = __builtin_shufflevector(k2, k2, 0, 1), k2h = __builtin_shufflevector(k2, k2, 2, 3);
    f32x2 k3l = __builtin_shufflevector(k3, k3, 0, 1), k3h = __builtin_shufflevector(k3, k3, 2, 3);
    g01 = pf(wg0, k0l, g01); g23 = pf(wg0, k0h, g23);
    g01 = pf(wg1, k1l, g01); g23 = pf(wg1, k1h, g23);
    g01 = pf(wg2, k2l, g01); g23 = pf(wg2, k2h, g23);
    g01 = pf(wg3, k3l, g01); g23 = pf(wg3, k3h, g23);
    u01 = pf(wu0, k0l, u01); u23 = pf(wu0, k0h, u23);
    u01 = pf(wu1, k1l, u01); u23 = pf(wu1, k1h, u23);
    u01 = pf(wu2, k2l, u01); u23 = pf(wu2, k2h, u23);
    u01 = pf(wu3, k3l, u01); u23 = pf(wu3, k3h, u23);
  }
  float g0 = g01[0], g1 = g01[1], g2 = g23[0], g3 = g23[1];
  float u0 = u01[0], u1 = u01[1], u2 = u23[0], u3 = u23[1];
  #pragma unroll
  for (int off = 1; off < 64; off <<= 1) {
    g0 += __shfl_xor(g0, off); g1 += __shfl_xor(g1, off);
    g2 += __shfl_xor(g2, off); g3 += __shfl_xor(g3, off);
    u0 += __shfl_xor(u0, off); u1 += __shfl_xor(u1, off);
    u2 += __shfl_xor(u2, off); u3 += __shfl_xor(u3, off);
  }
  if (l == 0) {
    f32x4 o;
    o[0] = (g0 / (1.f + __expf(-g0))) * u0;
    o[1] = (g1 / (1.f + __expf(-g1))) * u1;
    o[2] = (g2 / (1.f + __expf(-g2))) * u2;
    o[3] = (g3 / (1.f + __expf(-g3))) * u3;
    *(f32x4*)(hm4i + (size_t)n * 4) = o;
  }
}

// -------- down 4-row GEMV (K=14336): h4r[r][n] = h4i[n][r] + dot -----------
__global__ __launch_bounds__(256) void k_gemv_down(const int* __restrict__ idx,
    const float* __restrict__ am, const float* __restrict__ hm4i,
    const float* __restrict__ h4i, float* __restrict__ h4r)
{
  __shared__ float code[16];
  if (threadIdx.x < 16) code[threadIdx.x] = NF4_TAB[threadIdx.x];
  __syncthreads();
  int wv = threadIdx.x >> 6, l = threadIdx.x & 63;
  int lhi = l >> 4;
  int n = blockIdx.x * 4 + wv;
  const int4* ip = (const int4*)(idx + (size_t)n * 14336);
  const float* ap = am + (size_t)n * 224;
  f32x2 a01 = {0.f, 0.f}, a23 = {0.f, 0.f};
  #pragma unroll 8
  for (int kk = 0; kk < 56; ++kk) {
    int4 iv = ip[kk * 64 + l];
    float sc = ap[kk * 4 + lhi];
    float w0 = code[iv.x] * sc, w1 = code[iv.y] * sc;
    float w2 = code[iv.z] * sc, w3 = code[iv.w] * sc;
    const float* A0 = hm4i + (kk * 256 + l * 4) * 4;
    f32x4 k0 = *(const f32x4*)(A0);
    f32x4 k1 = *(const f32x4*)(A0 + 4);
    f32x4 k2 = *(const f32x4*)(A0 + 8);
    f32x4 k3 = *(const f32x4*)(A0 + 12);
    a01 = pf(w0, __builtin_shufflevector(k0, k0, 0, 1), a01);
    a23 = pf(w0, __builtin_shufflevector(k0, k0, 2, 3), a23);
    a01 = pf(w1, __builtin_shufflevector(k1, k1, 0, 1), a01);
    a23 = pf(w1, __builtin_shufflevector(k1, k1, 2, 3), a23);
    a01 = pf(w2, __builtin_shufflevector(k2, k2, 0, 1), a01);
    a23 = pf(w2, __builtin_shufflevector(k2, k2, 2, 3), a23);
    a01 = pf(w3, __builtin_shufflevector(k3, k3, 0, 1), a01);
    a23 = pf(w3, __builtin_shufflevector(k3, k3, 2, 3), a23);
  }
  float a0 = a01[0], a1 = a01[1], a2 = a23[0], a3 = a23[1];
  #pragma unroll
  for (int off = 1; off < 64; off <<= 1) {
    a0 += __shfl_xor(a0, off); a1 += __shfl_xor(a1, off);
    a2 += __shfl_xor(a2, off); a3 += __shfl_xor(a3, off);
  }
  if (l == 0) {
    f32x4 hr = *(const f32x4*)(h4i + (size_t)n * 4);
    h4r[0 * 4096 + n] = hr[0] + a0;
    h4r[1 * 4096 + n] = hr[1] + a1;
    h4r[2 * 4096 + n] = hr[2] + a2;
    h4r[3 * 4096 + n] = hr[3] + a3;
  }
}

// -------- pool (parallel): one block per output column o -------------------
__global__ __launch_bounds__(256) void k_pool3(const float* __restrict__ h4r,
    const float* __restrict__ dpw, const float* __restrict__ dpb,
    float* __restrict__ out)
{
  int o = blockIdx.x;
  int tid = threadIdx.x, wv = tid >> 6, l = tid & 63;
  __shared__ float dsh[4], nsh[4];
  const float* row = h4r + wv * 4096;
  const float* wrow = dpw + (size_t)o * 4096;
  float d1 = 0.f, ss = 0.f;
  for (int d = l * 4; d < 4096; d += 256) {
    float4 v = *(const float4*)(row + d);
    float4 u = *(const float4*)(wrow + d);
    d1 += v.x*u.x + v.y*u.y + v.z*u.z + v.w*u.w;
    ss += v.x*v.x + v.y*v.y + v.z*v.z + v.w*v.w;
  }
  #pragma unroll
  for (int off = 1; off < 64; off <<= 1) {
    d1 += __shfl_xor(d1, off);
    ss += __shfl_xor(ss, off);
  }
  if (l == 0) { dsh[wv] = d1; nsh[wv] = fmaxf(sqrtf(ss), 1e-12f); }
  __syncthreads();
  if (tid < 2) {
    float b = dpb[o];
    float e1 = dsh[tid] / nsh[tid] + b;
    float e2 = dsh[tid + 2] / nsh[tid + 2] + b;
    out[tid * 50 + o] = e1 * e2;
  }
}

// ---------------------------------------------------------------------------
extern "C" void kernel_launch(void* const* d_in, const int* in_sizes, int n_in,
                              void* d_out, int out_size, void* d_ws, size_t ws_size,
                              hipStream_t stream) {
  const int*   ids   = (const int*)d_in[0];
  const int*   maskp = (const int*)d_in[1];
  const float* table = (const float*)d_in[2];
  const int* idxp[7];
  const float* amp[7];
  if (in_sizes[4] == in_sizes[3] / 64) {
    for (int i = 0; i < 7; ++i) {
      idxp[i] = (const int*)d_in[3 + 2 * i];
      amp[i]  = (const float*)d_in[4 + 2 * i];
    }
  } else {
    for (int i = 0; i < 7; ++i) {
      idxp[i] = (const int*)d_in[3 + i];
      amp[i]  = (const float*)d_in[10 + i];
    }
  }
  const float* rms1 = (const float*)d_in[17];
  const float* rms2w = (const float*)d_in[18];
  const float* dpw  = (const float*)d_in[19];
  const float* dpb  = (const float*)d_in[20];
  float* out = (float*)d_out;

  char* p = (char*)d_ws;
  int*      lastb  = (int*)p;      p += 256;
  float*    r4i    = (float*)p;    p += 4 * 4096 * 4;
  float*    q4p    = (float*)p;    p += 4 * 4096 * 4;
  float*    ao4i   = (float*)p;    p += 4 * 4096 * 4;
  float*    h4i    = (float*)p;    p += 4 * 4096 * 4;
  float*    h4r    = (float*)p;    p += 4 * 4096 * 4;
  float*    scores = (float*)p;    p += 4 * 32 * 512 * 4;              // 256 KiB
  float*    hm4i   = (float*)p;    p += (size_t)4 * DFF * 4 + 512;     // 224 KiB
  float*    rbar8  = (float*)p;    p += (size_t)8 * 8 * 4096 * 16 * 4; // 16 MiB
  float*    rbarS  = (float*)p;    p += (size_t)8 * 4096 * 16 * 4;     // 2 MiB
  uint16_t* rbuf   = (uint16_t*)p; p += (size_t)TOK * DMODEL * 2;      // 16 MiB
  uint16_t* wbuf   = (uint16_t*)p; p += (size_t)1024 * DMODEL * 2;     // 8 MiB
  float*    pbuf   = (float*)p;    p += (size_t)8 * 2048 * 1024 * 4;   // 64 MiB

  // A: rms1 all rows | dequant K | lastb + r4i   (2564 blocks)
  k_fusedA<<<2564, 256, 0, stream>>>(ids, table, rms1, rbuf,
      idxp[1], amp[1], wbuf, maskp, lastb, r4i);

  // q projection at the 4 last tokens
  k_gemv_q<<<1024, 256, 0, stream>>>(idxp[0], amp[0], r4i, q4p);

  // K projection (all tokens), split-K=8, XCD-swizzled
  k_gemmk<<<dim3(4, 8, 8), 512, 0, stream>>>(rbuf, wbuf, pbuf);

  // per-token: reduce partials + rope(k) + rope(q) + q.k  -> scores
  k_kscore<<<2048, 256, 0, stream>>>(pbuf, q4p, lastb, scores);

  // softmax + partial rbar over 64-j slices (512 blocks)  [V-proj eliminated]
  k_smrbar<<<512, 256, 0, stream>>>(scores, rbuf, maskp, lastb, rbar8);
  k_rbar_red<<<512, 256, 0, stream>>>(rbar8, rbarS);

  // ao = Wv . rbarS
  k_gemv_v<<<256, 256, 0, stream>>>(idxp[2], amp[2], rbarS, ao4i);

  // O projection + embed residual -> h4i
  k_gemv_o<<<1024, 256, 0, stream>>>(idxp[3], amp[3], ao4i, h4i, table, ids, lastb);

  // MLP (rms2 inlined in gu)
  k_gemv_gu<<<3584, 256, 0, stream>>>(idxp[4], amp[4], idxp[5], amp[5], h4i, rms2w, hm4i);
  k_gemv_down<<<1024, 256, 0, stream>>>(idxp[6], amp[6], hm4i, h4i, h4r);

  // pool + normalize + project + pairwise product
  k_pool3<<<50, 256, 0, stream>>>(h4r, dpw, dpb, out);
}

// Round 9
// 397.163 us; speedup vs baseline: 1.3606x; 1.1270x over previous
//
#include <hip/hip_runtime.h>
#include <stdint.h>
#include <math.h>

#define TOK 2048
#define DMODEL 4096
#define DFF 14336
#define SEQ 512

typedef float f32x4 __attribute__((ext_vector_type(4)));
typedef float f32x2 __attribute__((ext_vector_type(2)));
typedef short s16x8 __attribute__((ext_vector_type(8)));
typedef unsigned short u16x8 __attribute__((ext_vector_type(8)));

__constant__ float NF4_TAB[16] = {
  -1.0f, -0.6961928009986877f, -0.5250730514526367f, -0.39491748809814453f,
  -0.28444138169288635f, -0.18477343022823334f, -0.09105003625154495f, 0.0f,
  0.07958029955625534f, 0.16093020141124725f, 0.24611230194568634f,
  0.33791524171829224f, 0.44070982933044434f, 0.5626170039176941f,
  0.7229568362236023f, 1.0f };

__device__ __forceinline__ uint16_t f2bf(float f) {
  union { float f; uint32_t u; } x; x.f = f;
  uint32_t r = (x.u + 0x7FFFu + ((x.u >> 16) & 1u)) >> 16;
  return (uint16_t)r;
}
__device__ __forceinline__ float bf2f(uint16_t u) {
  union { uint32_t u; float f; } x; x.u = ((uint32_t)u) << 16;
  return x.f;
}
__device__ __forceinline__ f32x4 mfma16(s16x8 a, s16x8 b, f32x4 c) {
  return __builtin_amdgcn_mfma_f32_16x16x32_bf16(a, b, c, 0, 0, 0);
}
__device__ __forceinline__ void gload_lds16(const void* g, void* l) {
  __builtin_amdgcn_global_load_lds(
    (const __attribute__((address_space(1))) unsigned int*)g,
    (__attribute__((address_space(3))) unsigned int*)l, 16, 0, 0);
}
__device__ __forceinline__ f32x2 pf(float w, f32x2 v, f32x2 acc) {
  f32x2 wv = {w, w};
  return wv * v + acc;
}

// == fused A: [rms1 | dequant K | dequant V | lastb + r4i(from table)] ======
__global__ __launch_bounds__(256) void k_fusedA(const int* __restrict__ ids,
    const float* __restrict__ table, const float* __restrict__ w1,
    uint16_t* __restrict__ rbuf, const int* __restrict__ idxK,
    const float* __restrict__ amK, const int* __restrict__ idxV,
    const float* __restrict__ amV, uint16_t* __restrict__ wbuf,
    const int* __restrict__ maskp, int* __restrict__ lastb,
    float* __restrict__ r4i)
{
  int bid = blockIdx.x, tid = threadIdx.x;
  if (bid < 2048) {
    // ---- RMSNorm + embed gather, row t = bid -> rbuf swizzled bf16 ----
    int t = bid;
    int wv = tid >> 6, l = tid & 63;
    const float* src = table + (size_t)ids[t] * DMODEL;
    int d0 = tid * 16;
    float vals[16];
    float ss = 0.f;
    #pragma unroll
    for (int i = 0; i < 4; ++i) {
      float4 v4 = *(const float4*)(src + d0 + i * 4);
      vals[i*4+0] = v4.x; vals[i*4+1] = v4.y; vals[i*4+2] = v4.z; vals[i*4+3] = v4.w;
      ss += v4.x*v4.x + v4.y*v4.y + v4.z*v4.z + v4.w*v4.w;
    }
    #pragma unroll
    for (int off = 1; off < 64; off <<= 1) ss += __shfl_xor(ss, off);
    __shared__ float red[4];
    if (l == 0) red[wv] = ss;
    __syncthreads();
    float rs = rsqrtf((red[0]+red[1]+red[2]+red[3]) * (1.f/DMODEL) + 1e-5f);
    #pragma unroll
    for (int cth = 0; cth < 2; ++cth) {
      int dd = d0 + cth * 8;
      u16x8 pk;
      #pragma unroll
      for (int j = 0; j < 8; ++j) pk[j] = f2bf(vals[cth*8+j] * rs * w1[dd + j]);
      int dsw = (dd & ~63) | (((((dd >> 3) & 7) ^ (t & 7))) << 3);
      *(u16x8*)(rbuf + (size_t)t * DMODEL + dsw) = pk;
    }
  } else if (bid < 3072) {
    // ---- dequant K (bid in [2048,2560)) / V (bid in [2560,3072)) ----
    bool isV = bid >= 2560;
    const int* idx = isV ? idxV : idxK;
    const float* am = isV ? amV : amK;
    uint16_t* out = wbuf + (isV ? (size_t)1024 * DMODEL : 0);
    int base = bid - (isV ? 2560 : 2048);
    __shared__ float code[16];
    if (tid < 16) code[tid] = NF4_TAB[tid];
    __syncthreads();
    const int nch = 1024 * DMODEL / 8;
    for (int c = base * 256 + tid; c < nch; c += 512 * 256) {
      int e = c << 3;
      int row = e >> 12;
      int kc = e & 4095;
      float a = am[c >> 3];
      int4 i0 = *(const int4*)(idx + e);
      int4 i1 = *(const int4*)(idx + e + 4);
      u16x8 pk;
      pk[0] = f2bf(code[i0.x] * a);
      pk[1] = f2bf(code[i0.y] * a);
      pk[2] = f2bf(code[i0.z] * a);
      pk[3] = f2bf(code[i0.w] * a);
      pk[4] = f2bf(code[i1.x] * a);
      pk[5] = f2bf(code[i1.y] * a);
      pk[6] = f2bf(code[i1.z] * a);
      pk[7] = f2bf(code[i1.w] * a);
      int dk = (kc & ~63) | (((((kc >> 3) & 7) ^ (row & 7))) << 3);
      *(u16x8*)(out + (size_t)row * DMODEL + dk) = pk;
    }
  } else {
    // ---- lastb[b] + r4i[:, b] (rms1-normalized last-token row, f32) ----
    int b = bid - 3072;
    int wv = tid >> 6, l = tid & 63;
    __shared__ int redi[4];
    __shared__ float redf[4];
    int cnt = 0;
    for (int j = tid; j < SEQ; j += 256) cnt += (maskp[b * SEQ + j] > 0);
    #pragma unroll
    for (int off = 1; off < 64; off <<= 1) cnt += __shfl_xor(cnt, off);
    if (l == 0) redi[wv] = cnt;
    __syncthreads();
    int last = redi[0] + redi[1] + redi[2] + redi[3] - 1;
    if (tid == 0) lastb[b] = last;
    int t = b * SEQ + last;
    const float* src = table + (size_t)ids[t] * DMODEL;
    int d0 = tid * 16;
    float vals[16];
    float ss = 0.f;
    #pragma unroll
    for (int i = 0; i < 4; ++i) {
      float4 v4 = *(const float4*)(src + d0 + i * 4);
      vals[i*4+0] = v4.x; vals[i*4+1] = v4.y; vals[i*4+2] = v4.z; vals[i*4+3] = v4.w;
      ss += v4.x*v4.x + v4.y*v4.y + v4.z*v4.z + v4.w*v4.w;
    }
    #pragma unroll
    for (int off = 1; off < 64; off <<= 1) ss += __shfl_xor(ss, off);
    if (l == 0) redf[wv] = ss;
    __syncthreads();
    float rs = rsqrtf((redf[0]+redf[1]+redf[2]+redf[3]) * (1.f/DMODEL) + 1e-5f);
    #pragma unroll
    for (int i = 0; i < 16; ++i)
      r4i[(d0 + i) * 4 + b] = vals[i] * rs * w1[d0 + i];
  }
}

// ==== 8-phase 256x256 split-K(4) GEMM, kv = r @ Wkv^T, bf16 partials =======
__global__ __launch_bounds__(512, 2) void k_gemmkv(
    const uint16_t* __restrict__ A, const uint16_t* __restrict__ W,
    uint16_t* __restrict__ pout)
{
  constexpr int K = 4096;
  constexpr int NT = 16;
  __shared__ __align__(1024) uint16_t As_[2 * 256 * 64];
  __shared__ __align__(1024) uint16_t Bs_[2 * 256 * 64];
  const int tid = threadIdx.x;
  const int wid = tid >> 6, l = tid & 63;
  const int wr = wid >> 2, wc = wid & 3;
  int f = blockIdx.x + (blockIdx.y << 3) + (blockIdx.z << 6);
  int fs = ((f & 7) << 5) + (f >> 3);
  const int n0 = (fs & 7) * 256;
  const int m0 = ((fs >> 3) & 7) * 256;
  const int zq = fs >> 6;
  const size_t kbase = (size_t)zq * 1024;
  const int lrow = l >> 3, lcb = (l & 7) * 16;

  auto stA = [&](int t, int h) {
    int ta = (t < NT) ? t : (t - NT);
    const char* g = (const char*)A +
        ((size_t)(m0 + h * 128 + wid * 16 + lrow) * K + kbase + ta * 64) * 2 + lcb;
    char* s = (char*)As_ + (t & 1) * 32768 + h * 16384 + wid * 2048;
    gload_lds16(g, s);
    gload_lds16(g + (size_t)8 * K * 2, s + 1024);
  };
  auto stB = [&](int t, int h) {
    int ta = (t < NT) ? t : (t - NT);
    const char* g = (const char*)W +
        ((size_t)(n0 + h * 128 + wid * 16 + lrow) * K + kbase + ta * 64) * 2 + lcb;
    char* s = (char*)Bs_ + (t & 1) * 32768 + h * 16384 + wid * 2048;
    gload_lds16(g, s);
    gload_lds16(g + (size_t)8 * K * 2, s + 1024);
  };

  const int cb0 = (((l >> 4) << 4)) ^ ((l & 7) << 4);
  const int cb1 = (64 + ((l >> 4) << 4)) ^ ((l & 7) << 4);

  const f32x4 Z4 = {0.f, 0.f, 0.f, 0.f};
  f32x4 acc[8][4];
  #pragma unroll
  for (int i = 0; i < 8; ++i)
    #pragma unroll
    for (int j = 0; j < 4; ++j) acc[i][j] = Z4;
  s16x8 bfr[4][2];

#define VMW asm volatile("s_waitcnt vmcnt(6)" ::: "memory")
#define PHASE(DB, Q, READB, STG) {                                          \
    const char* abase = (const char*)As_ + (DB) * 32768;                    \
    s16x8 af[2][2];                                                         \
    _Pragma("unroll") for (int mm = 0; mm < 2; ++mm) {                      \
      int arow = ((2 * (2 * (Q) + mm) + wr) * 16 + (l & 15)) * 128;         \
      af[mm][0] = *(const s16x8*)(abase + arow + cb0);                      \
      af[mm][1] = *(const s16x8*)(abase + arow + cb1);                      \
    }                                                                       \
    if (READB) {                                                            \
      const char* bbase = (const char*)Bs_ + (DB) * 32768;                  \
      _Pragma("unroll") for (int nn = 0; nn < 4; ++nn) {                    \
        int brow = (wc * 64 + nn * 16 + (l & 15)) * 128;                    \
        bfr[nn][0] = *(const s16x8*)(bbase + brow + cb0);                   \
        bfr[nn][1] = *(const s16x8*)(bbase + brow + cb1);                   \
      }                                                                     \
    }                                                                       \
    STG;                                                                    \
    __builtin_amdgcn_s_barrier();                                           \
    asm volatile("s_waitcnt lgkmcnt(0)" ::: "memory");                      \
    __builtin_amdgcn_sched_barrier(0);                                      \
    __builtin_amdgcn_s_setprio(1);                                          \
    _Pragma("unroll") for (int mm = 0; mm < 2; ++mm)                        \
      _Pragma("unroll") for (int nn = 0; nn < 4; ++nn) {                    \
        acc[2 * (Q) + mm][nn] = mfma16(af[mm][0], bfr[nn][0], acc[2 * (Q) + mm][nn]); \
        acc[2 * (Q) + mm][nn] = mfma16(af[mm][1], bfr[nn][1], acc[2 * (Q) + mm][nn]); \
      }                                                                     \
    __builtin_amdgcn_s_setprio(0);                                          \
    __builtin_amdgcn_s_barrier();                                           \
  }

  stB(0, 0); stA(0, 0); stB(0, 1); stA(0, 1);
  stB(1, 0); stA(1, 0); stB(1, 1);
  VMW;
  __builtin_amdgcn_s_barrier();

  for (int it = 0; it < NT / 2; ++it) {
    int t0 = 2 * it, t1 = t0 + 1;
    PHASE(0, 0, 1, stA(t1, 1));
    PHASE(0, 1, 0, stB(t0 + 2, 0));
    PHASE(0, 2, 0, stA(t0 + 2, 0));
    PHASE(0, 3, 0, { stB(t0 + 2, 1); VMW; });
    PHASE(1, 0, 1, stA(t0 + 2, 1));
    PHASE(1, 1, 0, stB(t1 + 2, 0));
    PHASE(1, 2, 0, stA(t1 + 2, 0));
    PHASE(1, 3, 0, { stB(t1 + 2, 1); VMW; });
  }
  asm volatile("s_waitcnt vmcnt(0)" ::: "memory");
  __builtin_amdgcn_s_barrier();
#undef PHASE
#undef VMW

  uint16_t* po = pout + (size_t)zq * 2048 * 2048;
  #pragma unroll
  for (int mf = 0; mf < 8; ++mf)
    #pragma unroll
    for (int nf = 0; nf < 4; ++nf)
      #pragma unroll
      for (int r = 0; r < 4; ++r) {
        int row = m0 + (2 * mf + wr) * 16 + ((l >> 4) << 2) + r;
        int col = n0 + wc * 64 + nf * 16 + (l & 15);
        po[(size_t)row * 2048 + col] = f2bf(acc[mf][nf][r]);
      }
}

// ============ fused D: [redrope rows (bf16 partials) | q-GEMV] =============
__global__ __launch_bounds__(256) void k_fusedD(const uint16_t* __restrict__ p,
    uint16_t* __restrict__ kv, const int* __restrict__ idxQ,
    const float* __restrict__ amQ, const float* __restrict__ a4i,
    float* __restrict__ q4i)
{
  int bid = blockIdx.x, tid = threadIdx.x;
  if (bid < 2048) {
    int t = bid;
    const size_t zs = (size_t)2048 * 2048;
    auto sum4 = [&](int c) -> float {
      size_t o = (size_t)t * 2048 + c;
      return bf2f(p[o]) + bf2f(p[o + zs]) + bf2f(p[o + 2 * zs]) + bf2f(p[o + 3 * zs]);
    };
    float pos = (float)(t & (SEQ - 1));
    for (int pi = tid; pi < 512; pi += 256) {
      int hh = pi >> 6, j = pi & 63;
      int c1 = hh * 128 + j, c2 = c1 + 64;
      float s1 = sum4(c1), s2 = sum4(c2);
      float f = pos * expf(-(float)j * 0.14391156831212787f);
      float sn, cs;
      sincosf(f, &sn, &cs);
      kv[(size_t)t * 2048 + c1] = f2bf(s1 * cs - s2 * sn);
      kv[(size_t)t * 2048 + c2] = f2bf(s2 * cs + s1 * sn);
    }
    for (int c = 1024 + tid; c < 2048; c += 256)
      kv[(size_t)t * 2048 + c] = f2bf(sum4(c));
  } else {
    __shared__ float code[16];
    if (tid < 16) code[tid] = NF4_TAB[tid];
    __syncthreads();
    int wv = tid >> 6, l = tid & 63;
    int lhi = l >> 4;
    int n = (bid - 2048) * 4 + wv;
    const int4* ip = (const int4*)(idxQ + (size_t)n * 4096);
    const float* ap = amQ + (size_t)n * 64;
    f32x2 a01 = {0.f, 0.f}, a23 = {0.f, 0.f};
    #pragma unroll
    for (int kk = 0; kk < 16; ++kk) {
      int4 iv = ip[kk * 64 + l];
      float sc = ap[kk * 4 + lhi];
      float w0 = code[iv.x] * sc, w1 = code[iv.y] * sc;
      float w2 = code[iv.z] * sc, w3 = code[iv.w] * sc;
      const float* A0 = a4i + (kk * 256 + l * 4) * 4;
      f32x4 k0 = *(const f32x4*)(A0);
      f32x4 k1 = *(const f32x4*)(A0 + 4);
      f32x4 k2 = *(const f32x4*)(A0 + 8);
      f32x4 k3 = *(const f32x4*)(A0 + 12);
      a01 = pf(w0, __builtin_shufflevector(k0, k0, 0, 1), a01);
      a23 = pf(w0, __builtin_shufflevector(k0, k0, 2, 3), a23);
      a01 = pf(w1, __builtin_shufflevector(k1, k1, 0, 1), a01);
      a23 = pf(w1, __builtin_shufflevector(k1, k1, 2, 3), a23);
      a01 = pf(w2, __builtin_shufflevector(k2, k2, 0, 1), a01);
      a23 = pf(w2, __builtin_shufflevector(k2, k2, 2, 3), a23);
      a01 = pf(w3, __builtin_shufflevector(k3, k3, 0, 1), a01);
      a23 = pf(w3, __builtin_shufflevector(k3, k3, 2, 3), a23);
    }
    float a0 = a01[0], a1 = a01[1], a2 = a23[0], a3 = a23[1];
    #pragma unroll
    for (int off = 1; off < 64; off <<= 1) {
      a0 += __shfl_xor(a0, off); a1 += __shfl_xor(a1, off);
      a2 += __shfl_xor(a2, off); a3 += __shfl_xor(a3, off);
    }
    if (l == 0) {
      f32x4 o;
      o[0] = a0; o[1] = a1; o[2] = a2; o[3] = a3;
      *(f32x4*)(q4i + (size_t)n * 4) = o;
    }
  }
}

// -------- 4-query attention (rope on q inside), f32, interleaved q/ao ------
__global__ __launch_bounds__(256) void k_attn4(const float* __restrict__ q4i,
    const uint16_t* __restrict__ kv, const int* __restrict__ maskp,
    const int* __restrict__ lastb, float* __restrict__ ao4i)
{
  int hh = blockIdx.x, b = blockIdx.y;
  int kvh = hh >> 2;
  int tid = threadIdx.x;
  __shared__ float qs[128];
  __shared__ float sarr[512];
  __shared__ float red[256];
  __shared__ f32x2 oacc2[4][64];
  int last = lastb[b];
  if (tid < 128) {
    int d = tid, j = d & 63;
    float f = (float)last * expf(-(float)j * 0.14391156831212787f);
    float sn, cs;
    sincosf(f, &sn, &cs);
    float qd  = q4i[(hh * 128 + d) * 4 + b];
    float qd2 = (d < 64) ? q4i[(hh * 128 + d + 64) * 4 + b]
                         : q4i[(hh * 128 + d - 64) * 4 + b];
    float v = (d < 64) ? (qd * cs - qd2 * sn) : (qd * cs + qd2 * sn);
    qs[d] = v * 0.08838834764831845f;
  }
  __syncthreads();
  float sl[2];
  #pragma unroll
  for (int h2 = 0; h2 < 2; ++h2) {
    int jj = tid + h2 * 256;
    bool valid = (jj <= last) && (maskp[b * SEQ + jj] > 0);
    float s = -1e9f;
    if (valid) {
      s = 0.f;
      const uint16_t* kp = kv + ((size_t)(b * SEQ + jj)) * 2048 + kvh * 128;
      #pragma unroll
      for (int c = 0; c < 16; ++c) {
        u16x8 kvv = *(const u16x8*)(kp + c * 8);
        #pragma unroll
        for (int e = 0; e < 8; ++e)
          s = fmaf(qs[c * 8 + e], bf2f(kvv[e]), s);
      }
    }
    sarr[jj] = s;
    sl[h2] = s;
  }
  red[tid] = fmaxf(sl[0], sl[1]);
  __syncthreads();
  for (int s = 128; s > 0; s >>= 1) {
    if (tid < s) red[tid] = fmaxf(red[tid], red[tid + s]);
    __syncthreads();
  }
  float m = red[0];
  __syncthreads();
  float ps = 0.f;
  #pragma unroll
  for (int h2 = 0; h2 < 2; ++h2) {
    int jj = tid + h2 * 256;
    float pe = __expf(sarr[jj] - m);
    ps += pe;
    sarr[jj] = pe;
  }
  red[tid] = ps;
  __syncthreads();
  for (int s = 128; s > 0; s >>= 1) {
    if (tid < s) red[tid] += red[tid + s];
    __syncthreads();
  }
  float inv = 1.f / red[0];
  __syncthreads();
  int qd = tid >> 6, pr = tid & 63;
  f32x2 acc = {0.f, 0.f};
  const uint16_t* vp = kv + ((size_t)(b * SEQ + qd * 128)) * 2048 + 1024 + kvh * 128 + pr * 2;
  for (int j = 0; j < 128; ++j) {
    float pj = sarr[qd * 128 + j];
    uint32_t pair = *(const uint32_t*)(vp + (size_t)j * 2048);
    f32x2 v;
    v[0] = bf2f((uint16_t)(pair & 0xffff));
    v[1] = bf2f((uint16_t)(pair >> 16));
    acc = pf(pj, v, acc);
  }
  oacc2[qd][pr] = acc;
  __syncthreads();
  if (tid < 64) {
    f32x2 s = oacc2[0][tid] + oacc2[1][tid] + oacc2[2][tid] + oacc2[3][tid];
    ao4i[((size_t)(hh * 128 + tid * 2)) * 4 + b]     = s[0] * inv;
    ao4i[((size_t)(hh * 128 + tid * 2 + 1)) * 4 + b] = s[1] * inv;
  }
}

// -------- o-proj 4-row GEMV + embed residual -> h4i [4096][4] --------------
__global__ __launch_bounds__(256) void k_gemv_o(const int* __restrict__ idx,
    const float* __restrict__ am, const float* __restrict__ a4i,
    float* __restrict__ out4i, const float* __restrict__ table,
    const int* __restrict__ ids, const int* __restrict__ lastb)
{
  __shared__ float code[16];
  if (threadIdx.x < 16) code[threadIdx.x] = NF4_TAB[threadIdx.x];
  __syncthreads();
  int wv = threadIdx.x >> 6, l = threadIdx.x & 63;
  int lhi = l >> 4;
  int n = blockIdx.x * 4 + wv;
  const int4* ip = (const int4*)(idx + (size_t)n * 4096);
  const float* ap = am + (size_t)n * 64;
  f32x2 a01 = {0.f, 0.f}, a23 = {0.f, 0.f};
  #pragma unroll
  for (int kk = 0; kk < 16; ++kk) {
    int4 iv = ip[kk * 64 + l];
    float sc = ap[kk * 4 + lhi];
    float w0 = code[iv.x] * sc, w1 = code[iv.y] * sc;
    float w2 = code[iv.z] * sc, w3 = code[iv.w] * sc;
    const float* A0 = a4i + (kk * 256 + l * 4) * 4;
    f32x4 k0 = *(const f32x4*)(A0);
    f32x4 k1 = *(const f32x4*)(A0 + 4);
    f32x4 k2 = *(const f32x4*)(A0 + 8);
    f32x4 k3 = *(const f32x4*)(A0 + 12);
    a01 = pf(w0, __builtin_shufflevector(k0, k0, 0, 1), a01);
    a23 = pf(w0, __builtin_shufflevector(k0, k0, 2, 3), a23);
    a01 = pf(w1, __builtin_shufflevector(k1, k1, 0, 1), a01);
    a23 = pf(w1, __builtin_shufflevector(k1, k1, 2, 3), a23);
    a01 = pf(w2, __builtin_shufflevector(k2, k2, 0, 1), a01);
    a23 = pf(w2, __builtin_shufflevector(k2, k2, 2, 3), a23);
    a01 = pf(w3, __builtin_shufflevector(k3, k3, 0, 1), a01);
    a23 = pf(w3, __builtin_shufflevector(k3, k3, 2, 3), a23);
  }
  float a0 = a01[0], a1 = a01[1], a2 = a23[0], a3 = a23[1];
  #pragma unroll
  for (int off = 1; off < 64; off <<= 1) {
    a0 += __shfl_xor(a0, off); a1 += __shfl_xor(a1, off);
    a2 += __shfl_xor(a2, off); a3 += __shfl_xor(a3, off);
  }
  if (l == 0) {
    f32x4 o;
    o[0] = a0; o[1] = a1; o[2] = a2; o[3] = a3;
    #pragma unroll
    for (int r = 0; r < 4; ++r)
      o[r] += table[(size_t)ids[r * SEQ + lastb[r]] * DMODEL + n];
    *(f32x4*)(out4i + (size_t)n * 4) = o;
  }
}

// ==== gate+up GEMV with inline rms2 (per-block norm recompute, L2-hit) =====
__global__ __launch_bounds__(256) void k_gemv_gu(const int* __restrict__ idxg,
    const float* __restrict__ amg, const int* __restrict__ idxu,
    const float* __restrict__ amu, const float* __restrict__ h4i,
    const float* __restrict__ w2, float* __restrict__ hm4i)
{
  __shared__ float code[16];
  __shared__ f32x4 redv[4];
  int tid = threadIdx.x, wv = tid >> 6, l = tid & 63;
  if (tid < 16) code[tid] = NF4_TAB[tid];
  f32x4 ssv = {0.f, 0.f, 0.f, 0.f};
  for (int i = 0; i < 16; ++i) {
    f32x4 h = *(const f32x4*)(h4i + (size_t)(tid + i * 256) * 4);
    ssv += h * h;
  }
  #pragma unroll
  for (int off = 1; off < 64; off <<= 1) {
    ssv[0] += __shfl_xor(ssv[0], off);
    ssv[1] += __shfl_xor(ssv[1], off);
    ssv[2] += __shfl_xor(ssv[2], off);
    ssv[3] += __shfl_xor(ssv[3], off);
  }
  if (l == 0) redv[wv] = ssv;
  __syncthreads();
  f32x4 tot = redv[0] + redv[1] + redv[2] + redv[3];
  f32x4 rs;
  #pragma unroll
  for (int r = 0; r < 4; ++r) rs[r] = rsqrtf(tot[r] * (1.f / 4096.f) + 1e-5f);

  int lhi = l >> 4;
  int n = blockIdx.x * 4 + wv;
  const int4* ipg = (const int4*)(idxg + (size_t)n * 4096);
  const int4* ipu = (const int4*)(idxu + (size_t)n * 4096);
  const float* apg = amg + (size_t)n * 64;
  const float* apu = amu + (size_t)n * 64;
  f32x2 g01 = {0.f, 0.f}, g23 = {0.f, 0.f};
  f32x2 u01 = {0.f, 0.f}, u23 = {0.f, 0.f};
  #pragma unroll 8
  for (int kk = 0; kk < 16; ++kk) {
    int4 ig = ipg[kk * 64 + l];
    int4 iu = ipu[kk * 64 + l];
    float sg = apg[kk * 4 + lhi];
    float su = apu[kk * 4 + lhi];
    float wg0 = code[ig.x] * sg, wg1 = code[ig.y] * sg;
    float wg2 = code[ig.z] * sg, wg3 = code[ig.w] * sg;
    float wu0 = code[iu.x] * su, wu1 = code[iu.y] * su;
    float wu2 = code[iu.z] * su, wu3 = code[iu.w] * su;
    int kb = kk * 256 + l * 4;
    const float* H = h4i + (size_t)kb * 4;
    float4 w2v = *(const float4*)(w2 + kb);
    f32x4 k0 = (*(const f32x4*)(H))      * rs * w2v.x;
    f32x4 k1 = (*(const f32x4*)(H + 4))  * rs * w2v.y;
    f32x4 k2 = (*(const f32x4*)(H + 8))  * rs * w2v.z;
    f32x4 k3 = (*(const f32x4*)(H + 12)) * rs * w2v.w;
    f32x2 k0l = __builtin_shufflevector(k0, k0, 0, 1), k0h = __builtin_shufflevector(k0, k0, 2, 3);
    f32x2 k1l = __builtin_shufflevector(k1, k1, 0, 1), k1h = __builtin_shufflevector(k1, k1, 2, 3);
    f32x2 k2l = __builtin_shufflevector(k2, k2, 0, 1), k2h = __builtin_shufflevector(k2, k2, 2, 3);
    f32x2 k3l = __builtin_shufflevector(k3, k3, 0, 1), k3h = __builtin_shufflevector(k3, k3, 2, 3);
    g01 = pf(wg0, k0l, g01); g23 = pf(wg0, k0h, g23);
    g01 = pf(wg1, k1l, g01); g23 = pf(wg1, k1h, g23);
    g01 = pf(wg2, k2l, g01); g23 = pf(wg2, k2h, g23);
    g01 = pf(wg3, k3l, g01); g23 = pf(wg3, k3h, g23);
    u01 = pf(wu0, k0l, u01); u23 = pf(wu0, k0h, u23);
    u01 = pf(wu1, k1l, u01); u23 = pf(wu1, k1h, u23);
    u01 = pf(wu2, k2l, u01); u23 = pf(wu2, k2h, u23);
    u01 = pf(wu3, k3l, u01); u23 = pf(wu3, k3h, u23);
  }
  float g0 = g01[0], g1 = g01[1], g2 = g23[0], g3 = g23[1];
  float u0 = u01[0], u1 = u01[1], u2 = u23[0], u3 = u23[1];
  #pragma unroll
  for (int off = 1; off < 64; off <<= 1) {
    g0 += __shfl_xor(g0, off); g1 += __shfl_xor(g1, off);
    g2 += __shfl_xor(g2, off); g3 += __shfl_xor(g3, off);
    u0 += __shfl_xor(u0, off); u1 += __shfl_xor(u1, off);
    u2 += __shfl_xor(u2, off); u3 += __shfl_xor(u3, off);
  }
  if (l == 0) {
    f32x4 o;
    o[0] = (g0 / (1.f + __expf(-g0))) * u0;
    o[1] = (g1 / (1.f + __expf(-g1))) * u1;
    o[2] = (g2 / (1.f + __expf(-g2))) * u2;
    o[3] = (g3 / (1.f + __expf(-g3))) * u3;
    *(f32x4*)(hm4i + (size_t)n * 4) = o;
  }
}

// -------- down 4-row GEMV (K=14336): h4r[r][n] = h4i[n][r] + dot -----------
__global__ __launch_bounds__(256) void k_gemv_down(const int* __restrict__ idx,
    const float* __restrict__ am, const float* __restrict__ hm4i,
    const float* __restrict__ h4i, float* __restrict__ h4r)
{
  __shared__ float code[16];
  if (threadIdx.x < 16) code[threadIdx.x] = NF4_TAB[threadIdx.x];
  __syncthreads();
  int wv = threadIdx.x >> 6, l = threadIdx.x & 63;
  int lhi = l >> 4;
  int n = blockIdx.x * 4 + wv;
  const int4* ip = (const int4*)(idx + (size_t)n * 14336);
  const float* ap = am + (size_t)n * 224;
  f32x2 a01 = {0.f, 0.f}, a23 = {0.f, 0.f};
  #pragma unroll 8
  for (int kk = 0; kk < 56; ++kk) {
    int4 iv = ip[kk * 64 + l];
    float sc = ap[kk * 4 + lhi];
    float w0 = code[iv.x] * sc, w1 = code[iv.y] * sc;
    float w2 = code[iv.z] * sc, w3 = code[iv.w] * sc;
    const float* A0 = hm4i + (kk * 256 + l * 4) * 4;
    f32x4 k0 = *(const f32x4*)(A0);
    f32x4 k1 = *(const f32x4*)(A0 + 4);
    f32x4 k2 = *(const f32x4*)(A0 + 8);
    f32x4 k3 = *(const f32x4*)(A0 + 12);
    a01 = pf(w0, __builtin_shufflevector(k0, k0, 0, 1), a01);
    a23 = pf(w0, __builtin_shufflevector(k0, k0, 2, 3), a23);
    a01 = pf(w1, __builtin_shufflevector(k1, k1, 0, 1), a01);
    a23 = pf(w1, __builtin_shufflevector(k1, k1, 2, 3), a23);
    a01 = pf(w2, __builtin_shufflevector(k2, k2, 0, 1), a01);
    a23 = pf(w2, __builtin_shufflevector(k2, k2, 2, 3), a23);
    a01 = pf(w3, __builtin_shufflevector(k3, k3, 0, 1), a01);
    a23 = pf(w3, __builtin_shufflevector(k3, k3, 2, 3), a23);
  }
  float a0 = a01[0], a1 = a01[1], a2 = a23[0], a3 = a23[1];
  #pragma unroll
  for (int off = 1; off < 64; off <<= 1) {
    a0 += __shfl_xor(a0, off); a1 += __shfl_xor(a1, off);
    a2 += __shfl_xor(a2, off); a3 += __shfl_xor(a3, off);
  }
  if (l == 0) {
    f32x4 hr = *(const f32x4*)(h4i + (size_t)n * 4);
    h4r[0 * 4096 + n] = hr[0] + a0;
    h4r[1 * 4096 + n] = hr[1] + a1;
    h4r[2 * 4096 + n] = hr[2] + a2;
    h4r[3 * 4096 + n] = hr[3] + a3;
  }
}

// -------- pool (parallel): one block per output column o -------------------
__global__ __launch_bounds__(256) void k_pool3(const float* __restrict__ h4r,
    const float* __restrict__ dpw, const float* __restrict__ dpb,
    float* __restrict__ out)
{
  int o = blockIdx.x;
  int tid = threadIdx.x, wv = tid >> 6, l = tid & 63;
  __shared__ float dsh[4], nsh[4];
  const float* row = h4r + wv * 4096;
  const float* wrow = dpw + (size_t)o * 4096;
  float d1 = 0.f, ss = 0.f;
  for (int d = l * 4; d < 4096; d += 256) {
    float4 v = *(const float4*)(row + d);
    float4 u = *(const float4*)(wrow + d);
    d1 += v.x*u.x + v.y*u.y + v.z*u.z + v.w*u.w;
    ss += v.x*v.x + v.y*v.y + v.z*v.z + v.w*v.w;
  }
  #pragma unroll
  for (int off = 1; off < 64; off <<= 1) {
    d1 += __shfl_xor(d1, off);
    ss += __shfl_xor(ss, off);
  }
  if (l == 0) { dsh[wv] = d1; nsh[wv] = fmaxf(sqrtf(ss), 1e-12f); }
  __syncthreads();
  if (tid < 2) {
    float b = dpb[o];
    float e1 = dsh[tid] / nsh[tid] + b;
    float e2 = dsh[tid + 2] / nsh[tid + 2] + b;
    out[tid * 50 + o] = e1 * e2;
  }
}

// ---------------------------------------------------------------------------
extern "C" void kernel_launch(void* const* d_in, const int* in_sizes, int n_in,
                              void* d_out, int out_size, void* d_ws, size_t ws_size,
                              hipStream_t stream) {
  const int*   ids   = (const int*)d_in[0];
  const int*   maskp = (const int*)d_in[1];
  const float* table = (const float*)d_in[2];
  const int* idxp[7];
  const float* amp[7];
  if (in_sizes[4] == in_sizes[3] / 64) {
    for (int i = 0; i < 7; ++i) {
      idxp[i] = (const int*)d_in[3 + 2 * i];
      amp[i]  = (const float*)d_in[4 + 2 * i];
    }
  } else {
    for (int i = 0; i < 7; ++i) {
      idxp[i] = (const int*)d_in[3 + i];
      amp[i]  = (const float*)d_in[10 + i];
    }
  }
  const float* rms1 = (const float*)d_in[17];
  const float* rms2w = (const float*)d_in[18];
  const float* dpw  = (const float*)d_in[19];
  const float* dpb  = (const float*)d_in[20];
  float* out = (float*)d_out;

  char* p = (char*)d_ws;
  int*      lastb = (int*)p;      p += 256;
  float*    r4i   = (float*)p;    p += 4 * 4096 * 4;
  float*    q4i   = (float*)p;    p += 4 * 4096 * 4;
  float*    ao4i  = (float*)p;    p += 4 * 4096 * 4;
  float*    h4i   = (float*)p;    p += 4 * 4096 * 4;
  float*    h4r   = (float*)p;    p += 4 * 4096 * 4;
  float*    hm4i  = (float*)p;    p += (size_t)4 * DFF * 4 + 512;      // 224 KiB
  uint16_t* kvbuf = (uint16_t*)p; p += (size_t)TOK * 2048 * 2;         // 8 MiB
  uint16_t* rbuf  = (uint16_t*)p; p += (size_t)TOK * DMODEL * 2;       // 16 MiB
  uint16_t* wbuf  = (uint16_t*)p; p += (size_t)2048 * DMODEL * 2;      // 16 MiB
  uint16_t* pbuf  = (uint16_t*)p; p += (size_t)4 * 2048 * 2048 * 2;    // 32 MiB

  // A: rms1 | dequant K | dequant V | lastb + r4i    (3076 blocks)
  k_fusedA<<<3076, 256, 0, stream>>>(ids, table, rms1, rbuf,
      idxp[1], amp[1], idxp[2], amp[2], wbuf, maskp, lastb, r4i);

  // K,V projections (all tokens), split-K=4, XCD-swizzled, bf16 partials
  k_gemmkv<<<dim3(8, 8, 4), 512, 0, stream>>>(rbuf, wbuf, pbuf);

  // D: split-K reduce + rope  |  q-GEMV   (3072 blocks)
  k_fusedD<<<3072, 256, 0, stream>>>(pbuf, kvbuf, idxp[0], amp[0], r4i, q4i);

  // attention for 4 queries
  k_attn4<<<dim3(32, 4), 256, 0, stream>>>(q4i, kvbuf, maskp, lastb, ao4i);

  // O projection + embed residual -> h4i
  k_gemv_o<<<1024, 256, 0, stream>>>(idxp[3], amp[3], ao4i, h4i, table, ids, lastb);

  // MLP (rms2 inlined in gu)
  k_gemv_gu<<<3584, 256, 0, stream>>>(idxp[4], amp[4], idxp[5], amp[5], h4i, rms2w, hm4i);
  k_gemv_down<<<1024, 256, 0, stream>>>(idxp[6], amp[6], hm4i, h4i, h4r);

  // pool + normalize + project + pairwise product
  k_pool3<<<50, 256, 0, stream>>>(h4r, dpw, dpb, out);
}

// Round 10
// 371.927 us; speedup vs baseline: 1.4529x; 1.0679x over previous
//
#include <hip/hip_runtime.h>
#include <stdint.h>
#include <math.h>

#define TOK 2048
#define DMODEL 4096
#define DFF 14336
#define SEQ 512

typedef float f32x4 __attribute__((ext_vector_type(4)));
typedef float f32x2 __attribute__((ext_vector_type(2)));
typedef short s16x8 __attribute__((ext_vector_type(8)));
typedef unsigned short u16x8 __attribute__((ext_vector_type(8)));

__constant__ float NF4_TAB[16] = {
  -1.0f, -0.6961928009986877f, -0.5250730514526367f, -0.39491748809814453f,
  -0.28444138169288635f, -0.18477343022823334f, -0.09105003625154495f, 0.0f,
  0.07958029955625534f, 0.16093020141124725f, 0.24611230194568634f,
  0.33791524171829224f, 0.44070982933044434f, 0.5626170039176941f,
  0.7229568362236023f, 1.0f };

__device__ __forceinline__ uint16_t f2bf(float f) {
  union { float f; uint32_t u; } x; x.f = f;
  uint32_t r = (x.u + 0x7FFFu + ((x.u >> 16) & 1u)) >> 16;
  return (uint16_t)r;
}
__device__ __forceinline__ float bf2f(uint16_t u) {
  union { uint32_t u; float f; } x; x.u = ((uint32_t)u) << 16;
  return x.f;
}
__device__ __forceinline__ f32x4 mfma16(s16x8 a, s16x8 b, f32x4 c) {
  return __builtin_amdgcn_mfma_f32_16x16x32_bf16(a, b, c, 0, 0, 0);
}
__device__ __forceinline__ void gload_lds16(const void* g, void* l) {
  __builtin_amdgcn_global_load_lds(
    (const __attribute__((address_space(1))) unsigned int*)g,
    (__attribute__((address_space(3))) unsigned int*)l, 16, 0, 0);
}
__device__ __forceinline__ f32x2 pf(float w, f32x2 v, f32x2 acc) {
  f32x2 wv = {w, w};
  return wv * v + acc;
}
// conflict-free NF4 lookup: lanes 0..15 hold the table, bpermute pulls lane iv
__device__ __forceinline__ float lut(int iv, float codeReg) {
  return __int_as_float(__builtin_amdgcn_ds_bpermute(iv << 2, __float_as_int(codeReg)));
}

// == fused A: [rms1 | dequant K | dequant V | lastb + r4i(from table)] ======
__global__ __launch_bounds__(256) void k_fusedA(const int* __restrict__ ids,
    const float* __restrict__ table, const float* __restrict__ w1,
    uint16_t* __restrict__ rbuf, const int* __restrict__ idxK,
    const float* __restrict__ amK, const int* __restrict__ idxV,
    const float* __restrict__ amV, uint16_t* __restrict__ wbuf,
    const int* __restrict__ maskp, int* __restrict__ lastb,
    float* __restrict__ r4i)
{
  int bid = blockIdx.x, tid = threadIdx.x;
  if (bid < 2048) {
    // ---- RMSNorm + embed gather, row t = bid -> rbuf swizzled bf16 ----
    int t = bid;
    int wv = tid >> 6, l = tid & 63;
    const float* src = table + (size_t)ids[t] * DMODEL;
    int d0 = tid * 16;
    float vals[16];
    float ss = 0.f;
    #pragma unroll
    for (int i = 0; i < 4; ++i) {
      float4 v4 = *(const float4*)(src + d0 + i * 4);
      vals[i*4+0] = v4.x; vals[i*4+1] = v4.y; vals[i*4+2] = v4.z; vals[i*4+3] = v4.w;
      ss += v4.x*v4.x + v4.y*v4.y + v4.z*v4.z + v4.w*v4.w;
    }
    #pragma unroll
    for (int off = 1; off < 64; off <<= 1) ss += __shfl_xor(ss, off);
    __shared__ float red[4];
    if (l == 0) red[wv] = ss;
    __syncthreads();
    float rs = rsqrtf((red[0]+red[1]+red[2]+red[3]) * (1.f/DMODEL) + 1e-5f);
    #pragma unroll
    for (int cth = 0; cth < 2; ++cth) {
      int dd = d0 + cth * 8;
      u16x8 pk;
      #pragma unroll
      for (int j = 0; j < 8; ++j) pk[j] = f2bf(vals[cth*8+j] * rs * w1[dd + j]);
      int dsw = (dd & ~63) | (((((dd >> 3) & 7) ^ (t & 7))) << 3);
      *(u16x8*)(rbuf + (size_t)t * DMODEL + dsw) = pk;
    }
  } else if (bid < 3072) {
    // ---- dequant K (bid in [2048,2560)) / V (bid in [2560,3072)) ----
    bool isV = bid >= 2560;
    const int* idx = isV ? idxV : idxK;
    const float* am = isV ? amV : amK;
    uint16_t* out = wbuf + (isV ? (size_t)1024 * DMODEL : 0);
    int base = bid - (isV ? 2560 : 2048);
    float codeReg = NF4_TAB[tid & 15];
    const int nch = 1024 * DMODEL / 8;
    for (int c = base * 256 + tid; c < nch; c += 512 * 256) {
      int e = c << 3;
      int row = e >> 12;
      int kc = e & 4095;
      float a = am[c >> 3];
      int4 i0 = *(const int4*)(idx + e);
      int4 i1 = *(const int4*)(idx + e + 4);
      u16x8 pk;
      pk[0] = f2bf(lut(i0.x, codeReg) * a);
      pk[1] = f2bf(lut(i0.y, codeReg) * a);
      pk[2] = f2bf(lut(i0.z, codeReg) * a);
      pk[3] = f2bf(lut(i0.w, codeReg) * a);
      pk[4] = f2bf(lut(i1.x, codeReg) * a);
      pk[5] = f2bf(lut(i1.y, codeReg) * a);
      pk[6] = f2bf(lut(i1.z, codeReg) * a);
      pk[7] = f2bf(lut(i1.w, codeReg) * a);
      int dk = (kc & ~63) | (((((kc >> 3) & 7) ^ (row & 7))) << 3);
      *(u16x8*)(out + (size_t)row * DMODEL + dk) = pk;
    }
  } else {
    // ---- lastb[b] + r4i[:, b] (rms1-normalized last-token row, f32) ----
    int b = bid - 3072;
    int wv = tid >> 6, l = tid & 63;
    __shared__ int redi[4];
    __shared__ float redf[4];
    int cnt = 0;
    for (int j = tid; j < SEQ; j += 256) cnt += (maskp[b * SEQ + j] > 0);
    #pragma unroll
    for (int off = 1; off < 64; off <<= 1) cnt += __shfl_xor(cnt, off);
    if (l == 0) redi[wv] = cnt;
    __syncthreads();
    int last = redi[0] + redi[1] + redi[2] + redi[3] - 1;
    if (tid == 0) lastb[b] = last;
    int t = b * SEQ + last;
    const float* src = table + (size_t)ids[t] * DMODEL;
    int d0 = tid * 16;
    float vals[16];
    float ss = 0.f;
    #pragma unroll
    for (int i = 0; i < 4; ++i) {
      float4 v4 = *(const float4*)(src + d0 + i * 4);
      vals[i*4+0] = v4.x; vals[i*4+1] = v4.y; vals[i*4+2] = v4.z; vals[i*4+3] = v4.w;
      ss += v4.x*v4.x + v4.y*v4.y + v4.z*v4.z + v4.w*v4.w;
    }
    #pragma unroll
    for (int off = 1; off < 64; off <<= 1) ss += __shfl_xor(ss, off);
    if (l == 0) redf[wv] = ss;
    __syncthreads();
    float rs = rsqrtf((redf[0]+redf[1]+redf[2]+redf[3]) * (1.f/DMODEL) + 1e-5f);
    #pragma unroll
    for (int i = 0; i < 16; ++i)
      r4i[(d0 + i) * 4 + b] = vals[i] * rs * w1[d0 + i];
  }
}

// ==== 8-phase 256x256 split-K(4) GEMM, kv = r @ Wkv^T, bf16 partials =======
__global__ __launch_bounds__(512, 2) void k_gemmkv(
    const uint16_t* __restrict__ A, const uint16_t* __restrict__ W,
    uint16_t* __restrict__ pout)
{
  constexpr int K = 4096;
  constexpr int NT = 16;
  __shared__ __align__(1024) uint16_t As_[2 * 256 * 64];
  __shared__ __align__(1024) uint16_t Bs_[2 * 256 * 64];
  const int tid = threadIdx.x;
  const int wid = tid >> 6, l = tid & 63;
  const int wr = wid >> 2, wc = wid & 3;
  int f = blockIdx.x + (blockIdx.y << 3) + (blockIdx.z << 6);
  int fs = ((f & 7) << 5) + (f >> 3);
  const int n0 = (fs & 7) * 256;
  const int m0 = ((fs >> 3) & 7) * 256;
  const int zq = fs >> 6;
  const size_t kbase = (size_t)zq * 1024;
  const int lrow = l >> 3, lcb = (l & 7) * 16;

  auto stA = [&](int t, int h) {
    int ta = (t < NT) ? t : (t - NT);
    const char* g = (const char*)A +
        ((size_t)(m0 + h * 128 + wid * 16 + lrow) * K + kbase + ta * 64) * 2 + lcb;
    char* s = (char*)As_ + (t & 1) * 32768 + h * 16384 + wid * 2048;
    gload_lds16(g, s);
    gload_lds16(g + (size_t)8 * K * 2, s + 1024);
  };
  auto stB = [&](int t, int h) {
    int ta = (t < NT) ? t : (t - NT);
    const char* g = (const char*)W +
        ((size_t)(n0 + h * 128 + wid * 16 + lrow) * K + kbase + ta * 64) * 2 + lcb;
    char* s = (char*)Bs_ + (t & 1) * 32768 + h * 16384 + wid * 2048;
    gload_lds16(g, s);
    gload_lds16(g + (size_t)8 * K * 2, s + 1024);
  };

  const int cb0 = (((l >> 4) << 4)) ^ ((l & 7) << 4);
  const int cb1 = (64 + ((l >> 4) << 4)) ^ ((l & 7) << 4);

  const f32x4 Z4 = {0.f, 0.f, 0.f, 0.f};
  f32x4 acc[8][4];
  #pragma unroll
  for (int i = 0; i < 8; ++i)
    #pragma unroll
    for (int j = 0; j < 4; ++j) acc[i][j] = Z4;
  s16x8 bfr[4][2];

#define VMW asm volatile("s_waitcnt vmcnt(6)" ::: "memory")
#define PHASE(DB, Q, READB, STG) {                                          \
    const char* abase = (const char*)As_ + (DB) * 32768;                    \
    s16x8 af[2][2];                                                         \
    _Pragma("unroll") for (int mm = 0; mm < 2; ++mm) {                      \
      int arow = ((2 * (2 * (Q) + mm) + wr) * 16 + (l & 15)) * 128;         \
      af[mm][0] = *(const s16x8*)(abase + arow + cb0);                      \
      af[mm][1] = *(const s16x8*)(abase + arow + cb1);                      \
    }                                                                       \
    if (READB) {                                                            \
      const char* bbase = (const char*)Bs_ + (DB) * 32768;                  \
      _Pragma("unroll") for (int nn = 0; nn < 4; ++nn) {                    \
        int brow = (wc * 64 + nn * 16 + (l & 15)) * 128;                    \
        bfr[nn][0] = *(const s16x8*)(bbase + brow + cb0);                   \
        bfr[nn][1] = *(const s16x8*)(bbase + brow + cb1);                   \
      }                                                                     \
    }                                                                       \
    STG;                                                                    \
    __builtin_amdgcn_s_barrier();                                           \
    asm volatile("s_waitcnt lgkmcnt(0)" ::: "memory");                      \
    __builtin_amdgcn_sched_barrier(0);                                      \
    __builtin_amdgcn_s_setprio(1);                                          \
    _Pragma("unroll") for (int mm = 0; mm < 2; ++mm)                        \
      _Pragma("unroll") for (int nn = 0; nn < 4; ++nn) {                    \
        acc[2 * (Q) + mm][nn] = mfma16(af[mm][0], bfr[nn][0], acc[2 * (Q) + mm][nn]); \
        acc[2 * (Q) + mm][nn] = mfma16(af[mm][1], bfr[nn][1], acc[2 * (Q) + mm][nn]); \
      }                                                                     \
    __builtin_amdgcn_s_setprio(0);                                          \
    __builtin_amdgcn_s_barrier();                                           \
  }

  stB(0, 0); stA(0, 0); stB(0, 1); stA(0, 1);
  stB(1, 0); stA(1, 0); stB(1, 1);
  VMW;
  __builtin_amdgcn_s_barrier();

  for (int it = 0; it < NT / 2; ++it) {
    int t0 = 2 * it, t1 = t0 + 1;
    PHASE(0, 0, 1, stA(t1, 1));
    PHASE(0, 1, 0, stB(t0 + 2, 0));
    PHASE(0, 2, 0, stA(t0 + 2, 0));
    PHASE(0, 3, 0, { stB(t0 + 2, 1); VMW; });
    PHASE(1, 0, 1, stA(t0 + 2, 1));
    PHASE(1, 1, 0, stB(t1 + 2, 0));
    PHASE(1, 2, 0, stA(t1 + 2, 0));
    PHASE(1, 3, 0, { stB(t1 + 2, 1); VMW; });
  }
  asm volatile("s_waitcnt vmcnt(0)" ::: "memory");
  __builtin_amdgcn_s_barrier();
#undef PHASE
#undef VMW

  uint16_t* po = pout + (size_t)zq * 2048 * 2048;
  #pragma unroll
  for (int mf = 0; mf < 8; ++mf)
    #pragma unroll
    for (int nf = 0; nf < 4; ++nf)
      #pragma unroll
      for (int r = 0; r < 4; ++r) {
        int row = m0 + (2 * mf + wr) * 16 + ((l >> 4) << 2) + r;
        int col = n0 + wc * 64 + nf * 16 + (l & 15);
        po[(size_t)row * 2048 + col] = f2bf(acc[mf][nf][r]);
      }
}

// ============ fused D: [redrope rows (bf16 partials) | q-GEMV] =============
__global__ __launch_bounds__(256) void k_fusedD(const uint16_t* __restrict__ p,
    uint16_t* __restrict__ kv, const int* __restrict__ idxQ,
    const float* __restrict__ amQ, const float* __restrict__ a4i,
    float* __restrict__ q4i)
{
  int bid = blockIdx.x, tid = threadIdx.x;
  if (bid < 2048) {
    int t = bid;
    const size_t zs = (size_t)2048 * 2048;
    auto sum4 = [&](int c) -> float {
      size_t o = (size_t)t * 2048 + c;
      return bf2f(p[o]) + bf2f(p[o + zs]) + bf2f(p[o + 2 * zs]) + bf2f(p[o + 3 * zs]);
    };
    float pos = (float)(t & (SEQ - 1));
    for (int pi = tid; pi < 512; pi += 256) {
      int hh = pi >> 6, j = pi & 63;
      int c1 = hh * 128 + j, c2 = c1 + 64;
      float s1 = sum4(c1), s2 = sum4(c2);
      float f = pos * expf(-(float)j * 0.14391156831212787f);
      float sn, cs;
      sincosf(f, &sn, &cs);
      kv[(size_t)t * 2048 + c1] = f2bf(s1 * cs - s2 * sn);
      kv[(size_t)t * 2048 + c2] = f2bf(s2 * cs + s1 * sn);
    }
    for (int c = 1024 + tid; c < 2048; c += 256)
      kv[(size_t)t * 2048 + c] = f2bf(sum4(c));
  } else {
    float codeReg = NF4_TAB[tid & 15];
    int wv = tid >> 6, l = tid & 63;
    int lhi = l >> 4;
    int n = (bid - 2048) * 4 + wv;
    const int4* ip = (const int4*)(idxQ + (size_t)n * 4096);
    const float* ap = amQ + (size_t)n * 64;
    f32x2 a01 = {0.f, 0.f}, a23 = {0.f, 0.f};
    #pragma unroll
    for (int kk = 0; kk < 16; ++kk) {
      int4 iv = ip[kk * 64 + l];
      float sc = ap[kk * 4 + lhi];
      float w0 = lut(iv.x, codeReg) * sc, w1 = lut(iv.y, codeReg) * sc;
      float w2 = lut(iv.z, codeReg) * sc, w3 = lut(iv.w, codeReg) * sc;
      const float* A0 = a4i + (kk * 256 + l * 4) * 4;
      f32x4 k0 = *(const f32x4*)(A0);
      f32x4 k1 = *(const f32x4*)(A0 + 4);
      f32x4 k2 = *(const f32x4*)(A0 + 8);
      f32x4 k3 = *(const f32x4*)(A0 + 12);
      a01 = pf(w0, __builtin_shufflevector(k0, k0, 0, 1), a01);
      a23 = pf(w0, __builtin_shufflevector(k0, k0, 2, 3), a23);
      a01 = pf(w1, __builtin_shufflevector(k1, k1, 0, 1), a01);
      a23 = pf(w1, __builtin_shufflevector(k1, k1, 2, 3), a23);
      a01 = pf(w2, __builtin_shufflevector(k2, k2, 0, 1), a01);
      a23 = pf(w2, __builtin_shufflevector(k2, k2, 2, 3), a23);
      a01 = pf(w3, __builtin_shufflevector(k3, k3, 0, 1), a01);
      a23 = pf(w3, __builtin_shufflevector(k3, k3, 2, 3), a23);
    }
    float a0 = a01[0], a1 = a01[1], a2 = a23[0], a3 = a23[1];
    #pragma unroll
    for (int off = 1; off < 64; off <<= 1) {
      a0 += __shfl_xor(a0, off); a1 += __shfl_xor(a1, off);
      a2 += __shfl_xor(a2, off); a3 += __shfl_xor(a3, off);
    }
    if (l == 0) {
      f32x4 o;
      o[0] = a0; o[1] = a1; o[2] = a2; o[3] = a3;
      *(f32x4*)(q4i + (size_t)n * 4) = o;
    }
  }
}

// -------- 4-query attention (rope on q inside), f32, interleaved q/ao ------
__global__ __launch_bounds__(256) void k_attn4(const float* __restrict__ q4i,
    const uint16_t* __restrict__ kv, const int* __restrict__ maskp,
    const int* __restrict__ lastb, float* __restrict__ ao4i)
{
  int hh = blockIdx.x, b = blockIdx.y;
  int kvh = hh >> 2;
  int tid = threadIdx.x;
  __shared__ float qs[128];
  __shared__ float sarr[512];
  __shared__ float red[256];
  __shared__ f32x2 oacc2[4][64];
  int last = lastb[b];
  if (tid < 128) {
    int d = tid, j = d & 63;
    float f = (float)last * expf(-(float)j * 0.14391156831212787f);
    float sn, cs;
    sincosf(f, &sn, &cs);
    float qd  = q4i[(hh * 128 + d) * 4 + b];
    float qd2 = (d < 64) ? q4i[(hh * 128 + d + 64) * 4 + b]
                         : q4i[(hh * 128 + d - 64) * 4 + b];
    float v = (d < 64) ? (qd * cs - qd2 * sn) : (qd * cs + qd2 * sn);
    qs[d] = v * 0.08838834764831845f;
  }
  __syncthreads();
  float sl[2];
  #pragma unroll
  for (int h2 = 0; h2 < 2; ++h2) {
    int jj = tid + h2 * 256;
    bool valid = (jj <= last) && (maskp[b * SEQ + jj] > 0);
    float s = -1e9f;
    if (valid) {
      s = 0.f;
      const uint16_t* kp = kv + ((size_t)(b * SEQ + jj)) * 2048 + kvh * 128;
      #pragma unroll
      for (int c = 0; c < 16; ++c) {
        u16x8 kvv = *(const u16x8*)(kp + c * 8);
        #pragma unroll
        for (int e = 0; e < 8; ++e)
          s = fmaf(qs[c * 8 + e], bf2f(kvv[e]), s);
      }
    }
    sarr[jj] = s;
    sl[h2] = s;
  }
  red[tid] = fmaxf(sl[0], sl[1]);
  __syncthreads();
  for (int s = 128; s > 0; s >>= 1) {
    if (tid < s) red[tid] = fmaxf(red[tid], red[tid + s]);
    __syncthreads();
  }
  float m = red[0];
  __syncthreads();
  float ps = 0.f;
  #pragma unroll
  for (int h2 = 0; h2 < 2; ++h2) {
    int jj = tid + h2 * 256;
    float pe = __expf(sarr[jj] - m);
    ps += pe;
    sarr[jj] = pe;
  }
  red[tid] = ps;
  __syncthreads();
  for (int s = 128; s > 0; s >>= 1) {
    if (tid < s) red[tid] += red[tid + s];
    __syncthreads();
  }
  float inv = 1.f / red[0];
  __syncthreads();
  int qd = tid >> 6, pr = tid & 63;
  f32x2 acc = {0.f, 0.f};
  const uint16_t* vp = kv + ((size_t)(b * SEQ + qd * 128)) * 2048 + 1024 + kvh * 128 + pr * 2;
  for (int j = 0; j < 128; ++j) {
    float pj = sarr[qd * 128 + j];
    uint32_t pair = *(const uint32_t*)(vp + (size_t)j * 2048);
    f32x2 v;
    v[0] = bf2f((uint16_t)(pair & 0xffff));
    v[1] = bf2f((uint16_t)(pair >> 16));
    acc = pf(pj, v, acc);
  }
  oacc2[qd][pr] = acc;
  __syncthreads();
  if (tid < 64) {
    f32x2 s = oacc2[0][tid] + oacc2[1][tid] + oacc2[2][tid] + oacc2[3][tid];
    ao4i[((size_t)(hh * 128 + tid * 2)) * 4 + b]     = s[0] * inv;
    ao4i[((size_t)(hh * 128 + tid * 2 + 1)) * 4 + b] = s[1] * inv;
  }
}

// -------- o-proj 4-row GEMV + embed residual -> h4i [4096][4] --------------
__global__ __launch_bounds__(256) void k_gemv_o(const int* __restrict__ idx,
    const float* __restrict__ am, const float* __restrict__ a4i,
    float* __restrict__ out4i, const float* __restrict__ table,
    const int* __restrict__ ids, const int* __restrict__ lastb)
{
  float codeReg = NF4_TAB[threadIdx.x & 15];
  int wv = threadIdx.x >> 6, l = threadIdx.x & 63;
  int lhi = l >> 4;
  int n = blockIdx.x * 4 + wv;
  const int4* ip = (const int4*)(idx + (size_t)n * 4096);
  const float* ap = am + (size_t)n * 64;
  f32x2 a01 = {0.f, 0.f}, a23 = {0.f, 0.f};
  #pragma unroll
  for (int kk = 0; kk < 16; ++kk) {
    int4 iv = ip[kk * 64 + l];
    float sc = ap[kk * 4 + lhi];
    float w0 = lut(iv.x, codeReg) * sc, w1 = lut(iv.y, codeReg) * sc;
    float w2 = lut(iv.z, codeReg) * sc, w3 = lut(iv.w, codeReg) * sc;
    const float* A0 = a4i + (kk * 256 + l * 4) * 4;
    f32x4 k0 = *(const f32x4*)(A0);
    f32x4 k1 = *(const f32x4*)(A0 + 4);
    f32x4 k2 = *(const f32x4*)(A0 + 8);
    f32x4 k3 = *(const f32x4*)(A0 + 12);
    a01 = pf(w0, __builtin_shufflevector(k0, k0, 0, 1), a01);
    a23 = pf(w0, __builtin_shufflevector(k0, k0, 2, 3), a23);
    a01 = pf(w1, __builtin_shufflevector(k1, k1, 0, 1), a01);
    a23 = pf(w1, __builtin_shufflevector(k1, k1, 2, 3), a23);
    a01 = pf(w2, __builtin_shufflevector(k2, k2, 0, 1), a01);
    a23 = pf(w2, __builtin_shufflevector(k2, k2, 2, 3), a23);
    a01 = pf(w3, __builtin_shufflevector(k3, k3, 0, 1), a01);
    a23 = pf(w3, __builtin_shufflevector(k3, k3, 2, 3), a23);
  }
  float a0 = a01[0], a1 = a01[1], a2 = a23[0], a3 = a23[1];
  #pragma unroll
  for (int off = 1; off < 64; off <<= 1) {
    a0 += __shfl_xor(a0, off); a1 += __shfl_xor(a1, off);
    a2 += __shfl_xor(a2, off); a3 += __shfl_xor(a3, off);
  }
  if (l == 0) {
    f32x4 o;
    o[0] = a0; o[1] = a1; o[2] = a2; o[3] = a3;
    #pragma unroll
    for (int r = 0; r < 4; ++r)
      o[r] += table[(size_t)ids[r * SEQ + lastb[r]] * DMODEL + n];
    *(f32x4*)(out4i + (size_t)n * 4) = o;
  }
}

// -------- rms2 on 4 rows (interleaved in/out), single block ----------------
__global__ __launch_bounds__(256) void k_rms2i(const float* __restrict__ h4i,
    const float* __restrict__ w, float* __restrict__ r2i)
{
  int tid = threadIdx.x, wv = tid >> 6, l = tid & 63;
  f32x4 vals[16];
  f32x4 ss = {0.f, 0.f, 0.f, 0.f};
  #pragma unroll
  for (int i = 0; i < 16; ++i) {
    vals[i] = *(const f32x4*)(h4i + (size_t)(tid + i * 256) * 4);
    ss += vals[i] * vals[i];
  }
  #pragma unroll
  for (int off = 1; off < 64; off <<= 1) {
    ss[0] += __shfl_xor(ss[0], off);
    ss[1] += __shfl_xor(ss[1], off);
    ss[2] += __shfl_xor(ss[2], off);
    ss[3] += __shfl_xor(ss[3], off);
  }
  __shared__ f32x4 red[4];
  if (l == 0) red[wv] = ss;
  __syncthreads();
  f32x4 tot = red[0] + red[1] + red[2] + red[3];
  f32x4 rs;
  #pragma unroll
  for (int r = 0; r < 4; ++r) rs[r] = rsqrtf(tot[r] * (1.f / 4096.f) + 1e-5f);
  #pragma unroll
  for (int i = 0; i < 16; ++i) {
    float wk = w[tid + i * 256];
    f32x4 o = vals[i] * rs * wk;
    *(f32x4*)(r2i + (size_t)(tid + i * 256) * 4) = o;
  }
}

// ==== gate+up GEMV (reads precomputed r2i) ================================
__global__ __launch_bounds__(256) void k_gemv_gu(const int* __restrict__ idxg,
    const float* __restrict__ amg, const int* __restrict__ idxu,
    const float* __restrict__ amu, const float* __restrict__ a4i,
    float* __restrict__ hm4i)
{
  float codeReg = NF4_TAB[threadIdx.x & 15];
  int wv = threadIdx.x >> 6, l = threadIdx.x & 63;
  int lhi = l >> 4;
  int n = blockIdx.x * 4 + wv;
  const int4* ipg = (const int4*)(idxg + (size_t)n * 4096);
  const int4* ipu = (const int4*)(idxu + (size_t)n * 4096);
  const float* apg = amg + (size_t)n * 64;
  const float* apu = amu + (size_t)n * 64;
  f32x2 g01 = {0.f, 0.f}, g23 = {0.f, 0.f};
  f32x2 u01 = {0.f, 0.f}, u23 = {0.f, 0.f};
  #pragma unroll 8
  for (int kk = 0; kk < 16; ++kk) {
    int4 ig = ipg[kk * 64 + l];
    int4 iu = ipu[kk * 64 + l];
    float sg = apg[kk * 4 + lhi];
    float su = apu[kk * 4 + lhi];
    float wg0 = lut(ig.x, codeReg) * sg, wg1 = lut(ig.y, codeReg) * sg;
    float wg2 = lut(ig.z, codeReg) * sg, wg3 = lut(ig.w, codeReg) * sg;
    float wu0 = lut(iu.x, codeReg) * su, wu1 = lut(iu.y, codeReg) * su;
    float wu2 = lut(iu.z, codeReg) * su, wu3 = lut(iu.w, codeReg) * su;
    const float* A0 = a4i + (kk * 256 + l * 4) * 4;
    f32x4 k0 = *(const f32x4*)(A0);
    f32x4 k1 = *(const f32x4*)(A0 + 4);
    f32x4 k2 = *(const f32x4*)(A0 + 8);
    f32x4 k3 = *(const f32x4*)(A0 + 12);
    f32x2 k0l = __builtin_shufflevector(k0, k0, 0, 1), k0h = __builtin_shufflevector(k0, k0, 2, 3);
    f32x2 k1l = __builtin_shufflevector(k1, k1, 0, 1), k1h = __builtin_shufflevector(k1, k1, 2, 3);
    f32x2 k2l = __builtin_shufflevector(k2, k2, 0, 1), k2h = __builtin_shufflevector(k2, k2, 2, 3);
    f32x2 k3l = __builtin_shufflevector(k3, k3, 0, 1), k3h = __builtin_shufflevector(k3, k3, 2, 3);
    g01 = pf(wg0, k0l, g01); g23 = pf(wg0, k0h, g23);
    g01 = pf(wg1, k1l, g01); g23 = pf(wg1, k1h, g23);
    g01 = pf(wg2, k2l, g01); g23 = pf(wg2, k2h, g23);
    g01 = pf(wg3, k3l, g01); g23 = pf(wg3, k3h, g23);
    u01 = pf(wu0, k0l, u01); u23 = pf(wu0, k0h, u23);
    u01 = pf(wu1, k1l, u01); u23 = pf(wu1, k1h, u23);
    u01 = pf(wu2, k2l, u01); u23 = pf(wu2, k2h, u23);
    u01 = pf(wu3, k3l, u01); u23 = pf(wu3, k3h, u23);
  }
  float g0 = g01[0], g1 = g01[1], g2 = g23[0], g3 = g23[1];
  float u0 = u01[0], u1 = u01[1], u2 = u23[0], u3 = u23[1];
  #pragma unroll
  for (int off = 1; off < 64; off <<= 1) {
    g0 += __shfl_xor(g0, off); g1 += __shfl_xor(g1, off);
    g2 += __shfl_xor(g2, off); g3 += __shfl_xor(g3, off);
    u0 += __shfl_xor(u0, off); u1 += __shfl_xor(u1, off);
    u2 += __shfl_xor(u2, off); u3 += __shfl_xor(u3, off);
  }
  if (l == 0) {
    f32x4 o;
    o[0] = (g0 / (1.f + __expf(-g0))) * u0;
    o[1] = (g1 / (1.f + __expf(-g1))) * u1;
    o[2] = (g2 / (1.f + __expf(-g2))) * u2;
    o[3] = (g3 / (1.f + __expf(-g3))) * u3;
    *(f32x4*)(hm4i + (size_t)n * 4) = o;
  }
}

// -------- down 4-row GEMV (K=14336): h4r[r][n] = h4i[n][r] + dot -----------
__global__ __launch_bounds__(256) void k_gemv_down(const int* __restrict__ idx,
    const float* __restrict__ am, const float* __restrict__ hm4i,
    const float* __restrict__ h4i, float* __restrict__ h4r)
{
  float codeReg = NF4_TAB[threadIdx.x & 15];
  int wv = threadIdx.x >> 6, l = threadIdx.x & 63;
  int lhi = l >> 4;
  int n = blockIdx.x * 4 + wv;
  const int4* ip = (const int4*)(idx + (size_t)n * 14336);
  const float* ap = am + (size_t)n * 224;
  f32x2 a01 = {0.f, 0.f}, a23 = {0.f, 0.f};
  #pragma unroll 8
  for (int kk = 0; kk < 56; ++kk) {
    int4 iv = ip[kk * 64 + l];
    float sc = ap[kk * 4 + lhi];
    float w0 = lut(iv.x, codeReg) * sc, w1 = lut(iv.y, codeReg) * sc;
    float w2 = lut(iv.z, codeReg) * sc, w3 = lut(iv.w, codeReg) * sc;
    const float* A0 = hm4i + (kk * 256 + l * 4) * 4;
    f32x4 k0 = *(const f32x4*)(A0);
    f32x4 k1 = *(const f32x4*)(A0 + 4);
    f32x4 k2 = *(const f32x4*)(A0 + 8);
    f32x4 k3 = *(const f32x4*)(A0 + 12);
    a01 = pf(w0, __builtin_shufflevector(k0, k0, 0, 1), a01);
    a23 = pf(w0, __builtin_shufflevector(k0, k0, 2, 3), a23);
    a01 = pf(w1, __builtin_shufflevector(k1, k1, 0, 1), a01);
    a23 = pf(w1, __builtin_shufflevector(k1, k1, 2, 3), a23);
    a01 = pf(w2, __builtin_shufflevector(k2, k2, 0, 1), a01);
    a23 = pf(w2, __builtin_shufflevector(k2, k2, 2, 3), a23);
    a01 = pf(w3, __builtin_shufflevector(k3, k3, 0, 1), a01);
    a23 = pf(w3, __builtin_shufflevector(k3, k3, 2, 3), a23);
  }
  float a0 = a01[0], a1 = a01[1], a2 = a23[0], a3 = a23[1];
  #pragma unroll
  for (int off = 1; off < 64; off <<= 1) {
    a0 += __shfl_xor(a0, off); a1 += __shfl_xor(a1, off);
    a2 += __shfl_xor(a2, off); a3 += __shfl_xor(a3, off);
  }
  if (l == 0) {
    f32x4 hr = *(const f32x4*)(h4i + (size_t)n * 4);
    h4r[0 * 4096 + n] = hr[0] + a0;
    h4r[1 * 4096 + n] = hr[1] + a1;
    h4r[2 * 4096 + n] = hr[2] + a2;
    h4r[3 * 4096 + n] = hr[3] + a3;
  }
}

// -------- pool (parallel): one block per output column o -------------------
__global__ __launch_bounds__(256) void k_pool3(const float* __restrict__ h4r,
    const float* __restrict__ dpw, const float* __restrict__ dpb,
    float* __restrict__ out)
{
  int o = blockIdx.x;
  int tid = threadIdx.x, wv = tid >> 6, l = tid & 63;
  __shared__ float dsh[4], nsh[4];
  const float* row = h4r + wv * 4096;
  const float* wrow = dpw + (size_t)o * 4096;
  float d1 = 0.f, ss = 0.f;
  for (int d = l * 4; d < 4096; d += 256) {
    float4 v = *(const float4*)(row + d);
    float4 u = *(const float4*)(wrow + d);
    d1 += v.x*u.x + v.y*u.y + v.z*u.z + v.w*u.w;
    ss += v.x*v.x + v.y*v.y + v.z*v.z + v.w*v.w;
  }
  #pragma unroll
  for (int off = 1; off < 64; off <<= 1) {
    d1 += __shfl_xor(d1, off);
    ss += __shfl_xor(ss, off);
  }
  if (l == 0) { dsh[wv] = d1; nsh[wv] = fmaxf(sqrtf(ss), 1e-12f); }
  __syncthreads();
  if (tid < 2) {
    float b = dpb[o];
    float e1 = dsh[tid] / nsh[tid] + b;
    float e2 = dsh[tid + 2] / nsh[tid + 2] + b;
    out[tid * 50 + o] = e1 * e2;
  }
}

// ---------------------------------------------------------------------------
extern "C" void kernel_launch(void* const* d_in, const int* in_sizes, int n_in,
                              void* d_out, int out_size, void* d_ws, size_t ws_size,
                              hipStream_t stream) {
  const int*   ids   = (const int*)d_in[0];
  const int*   maskp = (const int*)d_in[1];
  const float* table = (const float*)d_in[2];
  const int* idxp[7];
  const float* amp[7];
  if (in_sizes[4] == in_sizes[3] / 64) {
    for (int i = 0; i < 7; ++i) {
      idxp[i] = (const int*)d_in[3 + 2 * i];
      amp[i]  = (const float*)d_in[4 + 2 * i];
    }
  } else {
    for (int i = 0; i < 7; ++i) {
      idxp[i] = (const int*)d_in[3 + i];
      amp[i]  = (const float*)d_in[10 + i];
    }
  }
  const float* rms1 = (const float*)d_in[17];
  const float* rms2w = (const float*)d_in[18];
  const float* dpw  = (const float*)d_in[19];
  const float* dpb  = (const float*)d_in[20];
  float* out = (float*)d_out;

  char* p = (char*)d_ws;
  int*      lastb = (int*)p;      p += 256;
  float*    r4i   = (float*)p;    p += 4 * 4096 * 4;
  float*    q4i   = (float*)p;    p += 4 * 4096 * 4;
  float*    ao4i  = (float*)p;    p += 4 * 4096 * 4;
  float*    h4i   = (float*)p;    p += 4 * 4096 * 4;
  float*    r2i   = (float*)p;    p += 4 * 4096 * 4;
  float*    h4r   = (float*)p;    p += 4 * 4096 * 4;
  float*    hm4i  = (float*)p;    p += (size_t)4 * DFF * 4 + 512;      // 224 KiB
  uint16_t* kvbuf = (uint16_t*)p; p += (size_t)TOK * 2048 * 2;         // 8 MiB
  uint16_t* rbuf  = (uint16_t*)p; p += (size_t)TOK * DMODEL * 2;       // 16 MiB
  uint16_t* wbuf  = (uint16_t*)p; p += (size_t)2048 * DMODEL * 2;      // 16 MiB
  uint16_t* pbuf  = (uint16_t*)p; p += (size_t)4 * 2048 * 2048 * 2;    // 32 MiB

  // A: rms1 | dequant K | dequant V | lastb + r4i    (3076 blocks)
  k_fusedA<<<3076, 256, 0, stream>>>(ids, table, rms1, rbuf,
      idxp[1], amp[1], idxp[2], amp[2], wbuf, maskp, lastb, r4i);

  // K,V projections (all tokens), split-K=4, XCD-swizzled, bf16 partials
  k_gemmkv<<<dim3(8, 8, 4), 512, 0, stream>>>(rbuf, wbuf, pbuf);

  // D: split-K reduce + rope  |  q-GEMV   (3072 blocks)
  k_fusedD<<<3072, 256, 0, stream>>>(pbuf, kvbuf, idxp[0], amp[0], r4i, q4i);

  // attention for 4 queries
  k_attn4<<<dim3(32, 4), 256, 0, stream>>>(q4i, kvbuf, maskp, lastb, ao4i);

  // O projection + embed residual -> h4i
  k_gemv_o<<<1024, 256, 0, stream>>>(idxp[3], amp[3], ao4i, h4i, table, ids, lastb);

  // rms2 (tiny) + MLP
  k_rms2i<<<1, 256, 0, stream>>>(h4i, rms2w, r2i);
  k_gemv_gu<<<3584, 256, 0, stream>>>(idxp[4], amp[4], idxp[5], amp[5], r2i, hm4i);
  k_gemv_down<<<1024, 256, 0, stream>>>(idxp[6], amp[6], hm4i, h4i, h4r);

  // pool + normalize + project + pairwise product
  k_pool3<<<50, 256, 0, stream>>>(h4r, dpw, dpb, out);
}